// Round 11
// baseline (164.460 us; speedup 1.0000x reference)
//
#include <hip/hip_runtime.h>
#include <hip/hip_bf16.h>

// ---------------------------------------------------------------------------
// GCN: 3x gcn_conv + global_mean_pool + linear
//   h' = D^-1/2 (A+I) D^-1/2 (h W) + b
// Layer1 aggregates BEFORE GEMM ((AX)W == A(XW)), layers 2/3 after.
// dinv FOLDED into stored features; aggregation = pure gather+sum.
// F16 features + weights. Agg: ONE WAVE PER NODE, half-wave row gathers.
// Layer-3 agg FUSED into pool stage 1 (grid (G,8), wave-per-row, block-own
// partial slot — deterministic, no atomics, no A3 buffer).
// GEMMs: LDS-staged f16 MFMA, XOR-swizzled, single weight plane.
// Scan: 16-wave range-partitioned. 11 dispatches.
// ---------------------------------------------------------------------------

#define N_NODES_C  20000
#define N_GRAPHS_C 64
#define HID_C      512

typedef __attribute__((ext_vector_type(8))) _Float16 f16x8;
typedef __attribute__((ext_vector_type(8))) unsigned short u16x8;
typedef __attribute__((ext_vector_type(4))) float f32x4;

static __device__ __forceinline__ unsigned short f2h(float f) {
    _Float16 h = (_Float16)f;
    return __builtin_bit_cast(unsigned short, h);
}
static __device__ __forceinline__ float h2f(unsigned short u) {
    return (float)__builtin_bit_cast(_Float16, u);
}
static __device__ __forceinline__ float hu_lo(unsigned u) {
    return (float)__builtin_bit_cast(_Float16, (unsigned short)(u & 0xffffu));
}
static __device__ __forceinline__ float hu_hi(unsigned u) {
    return (float)__builtin_bit_cast(_Float16, (unsigned short)(u >> 16));
}

// 16-wave range-partitioned scan
__global__ __launch_bounds__(1024) void scan_kernel(const int* __restrict__ deg_cnt,
                                                    int* __restrict__ row_ptr,
                                                    int* __restrict__ cursor,
                                                    float* __restrict__ dinv, int n) {
    __shared__ int ws[16];
    int t = threadIdx.x;
    int wid = t >> 6, lane = t & 63;
    const int RANGE = (n + 15) >> 4;
    const int ROUNDS = (RANGE + 63) >> 6;
    int base = wid * RANGE;

    int s = 0;
    for (int r = 0; r < ROUNDS; ++r) {
        int off = r * 64 + lane;
        int idx = base + off;
        if (off < RANGE && idx < n) s += deg_cnt[idx];
    }
    #pragma unroll
    for (int o = 32; o > 0; o >>= 1) s += __shfl_xor(s, o);
    if (lane == 0) ws[wid] = s;
    __syncthreads();

    int carry = 0;
    for (int j = 0; j < wid; ++j) carry += ws[j];

    for (int r = 0; r < ROUNDS; ++r) {
        int off = r * 64 + lane;
        int idx = base + off;
        int v = (off < RANGE && idx < n) ? deg_cnt[idx] : 0;
        int x = v;
        #pragma unroll
        for (int o = 1; o < 64; o <<= 1) {
            int y = __shfl_up(x, o);
            if (lane >= o) x += y;
        }
        if (off < RANGE && idx < n) {
            int rp = carry + x - v;
            row_ptr[idx] = rp;
            cursor[idx]  = rp;
            dinv[idx]    = rsqrtf((float)(v + 1));
        }
        carry += __shfl(x, 63);
    }
    if (t == 1023) row_ptr[n] = carry;
}

static __device__ __forceinline__ void wconv_body(const float* __restrict__ W, int i,
                                                  int Kd, int Nd,
                                                  unsigned short* __restrict__ WT) {
    int k = i / Nd, n = i % Nd;
    WT[(size_t)n * Kd + k] = f2h(W[i]);
}

// Fused setup: edge-count + 3x weight transpose (f16) + graph bounds.
__global__ void prep_kernel(const int* __restrict__ dst, int* __restrict__ deg_cnt, int E,
                            const float* __restrict__ W1, const float* __restrict__ W2,
                            const float* __restrict__ W3,
                            unsigned short* __restrict__ W1T,
                            unsigned short* __restrict__ W2T,
                            unsigned short* __restrict__ W3T,
                            const int* __restrict__ batch, int n, int ngraphs,
                            int* __restrict__ gstart) {
    int t = blockIdx.x * blockDim.x + threadIdx.x;
    if (t < E) {
        atomicAdd(&deg_cnt[dst[t]], 1);
        return;
    }
    t -= E;
    if (t < 128 * 512) { wconv_body(W1, t, 128, 512, W1T); return; }
    t -= 128 * 512;
    if (t < 512 * 256) { wconv_body(W2, t, 512, 256, W2T); return; }
    t -= 512 * 256;
    if (t < 256 * 128) { wconv_body(W3, t, 256, 128, W3T); return; }
    t -= 256 * 128;
    {
        int i = t;
        if (i >= n) return;
        int b = batch[i];
        if (i == 0) {
            for (int g = 0; g <= b; ++g) gstart[g] = 0;
        } else {
            int bp = batch[i - 1];
            if (bp != b) for (int g = bp + 1; g <= b; ++g) gstart[g] = i;
        }
        if (i == n - 1) {
            for (int g = b + 1; g <= ngraphs; ++g) gstart[g] = n;
        }
    }
}

// Fused: CSR fill (scatter) + xs = f16(x*dinv)
__global__ void fillx_kernel(const int* __restrict__ src, const int* __restrict__ dst,
                             int* __restrict__ cursor, int* __restrict__ col_idx, int E,
                             const float* __restrict__ x, const float* __restrict__ dinv,
                             unsigned short* __restrict__ xs, int nrows) {
    int t = blockIdx.x * blockDim.x + threadIdx.x;
    if (t < E) {
        int d = dst[t];
        int pos = atomicAdd(&cursor[d], 1);
        col_idx[pos] = src[t];
    } else {
        int u = t - E;
        int row = u >> 5, q = u & 31;
        if (row >= nrows) return;
        float di = dinv[row];
        f32x4 v = *reinterpret_cast<const f32x4*>(&x[(size_t)row * 128 + q * 4]);
        ushort4 o;
        o.x = f2h(v.x * di); o.y = f2h(v.y * di);
        o.z = f2h(v.z * di); o.w = f2h(v.w * di);
        *reinterpret_cast<ushort4*>(&xs[(size_t)row * 128 + q * 4]) = o;
    }
}

// ---------------------------------------------------------------------------
// Aggregation: out[i] = dinv[i]*(hs[i] + sum_{e in(i)} hs[src]) (+bias)(relu)
// ONE WAVE PER NODE (4 nodes/block). Half-wave: lanes 0-31 edge j, lanes
// 32-63 edge j+1; CPL f16/lane. Unroll 4 steps = 8 edges in flight.
// ---------------------------------------------------------------------------
template <int F, bool BIAS, bool RELU>
__global__ __launch_bounds__(256) void agg_kernel(const unsigned short* __restrict__ hs,
                                                  const float* __restrict__ dinv,
                                                  const int* __restrict__ row_ptr,
                                                  const int* __restrict__ col_idx,
                                                  const float* __restrict__ bias,
                                                  unsigned short* __restrict__ out, int n) {
    constexpr int CPL = F / 32;         // 4 (F=128) or 8 (F=256)
    int tid = threadIdx.x;
    int wid = tid >> 6, lane = tid & 63;
    int h = lane >> 5, l32 = lane & 31;
    int i = blockIdx.x * 4 + wid;
    if (i >= n) return;                 // wave-uniform; no barriers in kernel
    int e0 = row_ptr[i], e1 = row_ptr[i + 1];

    float acc[CPL];
    #pragma unroll
    for (int v = 0; v < CPL; ++v) acc[v] = 0.f;

    if (h == 0) {
        const unsigned short* p = &hs[(size_t)i * F + l32 * CPL];
        if constexpr (CPL == 4) {
            uint2 u = *reinterpret_cast<const uint2*>(p);
            acc[0] = hu_lo(u.x); acc[1] = hu_hi(u.x);
            acc[2] = hu_lo(u.y); acc[3] = hu_hi(u.y);
        } else {
            uint4 u = *reinterpret_cast<const uint4*>(p);
            acc[0] = hu_lo(u.x); acc[1] = hu_hi(u.x);
            acc[2] = hu_lo(u.y); acc[3] = hu_hi(u.y);
            acc[4] = hu_lo(u.z); acc[5] = hu_hi(u.z);
            acc[6] = hu_lo(u.w); acc[7] = hu_hi(u.w);
        }
    }

    for (int base = e0; base < e1; base += 64) {
        int rem = e1 - base;
        int mm = rem < 64 ? rem : 64;
        int myidx = col_idx[base + (lane < mm ? lane : 0)];
        for (int j0 = 0; j0 < mm; j0 += 8) {
            #pragma unroll
            for (int k = 0; k < 4; ++k) {
                int j = j0 + 2 * k + h;
                int jc = j < mm ? j : 0;
                int srcn = __shfl(myidx, jc);
                float w = (j < mm) ? 1.f : 0.f;
                const unsigned short* p = &hs[(size_t)srcn * F + l32 * CPL];
                if constexpr (CPL == 4) {
                    uint2 u = *reinterpret_cast<const uint2*>(p);
                    acc[0] = fmaf(hu_lo(u.x), w, acc[0]);
                    acc[1] = fmaf(hu_hi(u.x), w, acc[1]);
                    acc[2] = fmaf(hu_lo(u.y), w, acc[2]);
                    acc[3] = fmaf(hu_hi(u.y), w, acc[3]);
                } else {
                    uint4 u = *reinterpret_cast<const uint4*>(p);
                    acc[0] = fmaf(hu_lo(u.x), w, acc[0]);
                    acc[1] = fmaf(hu_hi(u.x), w, acc[1]);
                    acc[2] = fmaf(hu_lo(u.y), w, acc[2]);
                    acc[3] = fmaf(hu_hi(u.y), w, acc[3]);
                    acc[4] = fmaf(hu_lo(u.z), w, acc[4]);
                    acc[5] = fmaf(hu_hi(u.z), w, acc[5]);
                    acc[6] = fmaf(hu_lo(u.w), w, acc[6]);
                    acc[7] = fmaf(hu_hi(u.w), w, acc[7]);
                }
            }
        }
    }

    #pragma unroll
    for (int v = 0; v < CPL; ++v) acc[v] += __shfl_xor(acc[v], 32);

    if (h == 0) {
        float di = dinv[i];
        unsigned short ov[CPL];
        #pragma unroll
        for (int v = 0; v < CPL; ++v) {
            float r = di * acc[v];
            if (BIAS) r += bias[l32 * CPL + v];
            if (RELU) r = fmaxf(r, 0.f);
            ov[v] = f2h(r);
        }
        if constexpr (CPL == 4) {
            uint2 o;
            o.x = (unsigned)ov[0] | ((unsigned)ov[1] << 16);
            o.y = (unsigned)ov[2] | ((unsigned)ov[3] << 16);
            *reinterpret_cast<uint2*>(&out[(size_t)i * F + l32 * CPL]) = o;
        } else {
            uint4 o;
            o.x = (unsigned)ov[0] | ((unsigned)ov[1] << 16);
            o.y = (unsigned)ov[2] | ((unsigned)ov[3] << 16);
            o.z = (unsigned)ov[4] | ((unsigned)ov[5] << 16);
            o.w = (unsigned)ov[6] | ((unsigned)ov[7] << 16);
            *reinterpret_cast<uint4*>(&out[(size_t)i * F + l32 * CPL]) = o;
        }
    }
}

// ---------------------------------------------------------------------------
// Layer-3 aggregation FUSED with pool stage 1. Grid (G, 8); block (g,y)
// owns rows i = gstart[g] + y*4 + wid, step 32 (8 slices x 4 waves).
// Per row: full agg (self + gathered neighbors, +bias, f32), accumulated
// into a per-wave running sum; block-reduce; write partial[g*8+y].
// Deterministic — each block writes only its own slot. No A3 buffer.
// ---------------------------------------------------------------------------
__global__ __launch_bounds__(256) void agg_pool_kernel(const unsigned short* __restrict__ hs,
                                                       const float* __restrict__ dinv,
                                                       const int* __restrict__ row_ptr,
                                                       const int* __restrict__ col_idx,
                                                       const float* __restrict__ bias,
                                                       const int* __restrict__ gstart,
                                                       float* __restrict__ partial) {
    constexpr int F = 128, CPL = 4;
    __shared__ float red[3 * F];
    int g = blockIdx.x, y = blockIdx.y;
    int tid = threadIdx.x;
    int wid = tid >> 6, lane = tid & 63;
    int h = lane >> 5, l32 = lane & 31;
    int s0 = gstart[g], s1 = gstart[g + 1];

    float sum[CPL] = {0.f, 0.f, 0.f, 0.f};

    for (int i = s0 + y * 4 + wid; i < s1; i += 32) {
        int e0 = row_ptr[i], e1 = row_ptr[i + 1];
        float acc[CPL] = {0.f, 0.f, 0.f, 0.f};

        if (h == 0) {
            uint2 u = *reinterpret_cast<const uint2*>(&hs[(size_t)i * F + l32 * CPL]);
            acc[0] = hu_lo(u.x); acc[1] = hu_hi(u.x);
            acc[2] = hu_lo(u.y); acc[3] = hu_hi(u.y);
        }
        for (int base = e0; base < e1; base += 64) {
            int rem = e1 - base;
            int mm = rem < 64 ? rem : 64;
            int myidx = col_idx[base + (lane < mm ? lane : 0)];
            for (int j0 = 0; j0 < mm; j0 += 8) {
                #pragma unroll
                for (int k = 0; k < 4; ++k) {
                    int j = j0 + 2 * k + h;
                    int jc = j < mm ? j : 0;
                    int srcn = __shfl(myidx, jc);
                    float w = (j < mm) ? 1.f : 0.f;
                    uint2 u = *reinterpret_cast<const uint2*>(&hs[(size_t)srcn * F + l32 * CPL]);
                    acc[0] = fmaf(hu_lo(u.x), w, acc[0]);
                    acc[1] = fmaf(hu_hi(u.x), w, acc[1]);
                    acc[2] = fmaf(hu_lo(u.y), w, acc[2]);
                    acc[3] = fmaf(hu_hi(u.y), w, acc[3]);
                }
            }
        }
        #pragma unroll
        for (int v = 0; v < CPL; ++v) acc[v] += __shfl_xor(acc[v], 32);
        if (h == 0) {
            float di = dinv[i];
            #pragma unroll
            for (int v = 0; v < CPL; ++v)
                sum[v] += di * acc[v] + bias[l32 * CPL + v];
        }
    }

    // block reduce over 4 waves (h==0 lanes hold data)
    if (wid > 0 && h == 0)
        *reinterpret_cast<float4*>(&red[(wid - 1) * F + l32 * CPL]) =
            make_float4(sum[0], sum[1], sum[2], sum[3]);
    __syncthreads();
    if (wid == 0 && h == 0) {
        #pragma unroll
        for (int w = 0; w < 3; ++w)
            #pragma unroll
            for (int v = 0; v < CPL; ++v) sum[v] += red[w * F + l32 * CPL + v];
        #pragma unroll
        for (int v = 0; v < CPL; ++v)
            partial[(size_t)(g * 8 + y) * F + l32 * CPL + v] = sum[v];
    }
}

// ---------------------------------------------------------------------------
// MFMA f16 GEMM: C[M,N] = A[M,K] @ W[K,N] (+bias)(relu)(*dinv[row]) -> f16
// A [M][K] f16, WT [N][K] f16. BK=64, 256 threads = 4 waves (2x2).
// LDS XOR-swizzled (ushort units): idx = row*64 + (k ^ ((row&7)<<3))
// ---------------------------------------------------------------------------
template <int K, int N, int BM, int BN, bool BIAS, bool RELU, bool SCALE>
__global__ __launch_bounds__(256) void gemm_mfma(const unsigned short* __restrict__ A,
                                                 const unsigned short* __restrict__ WT,
                                                 const float* __restrict__ bias,
                                                 const float* __restrict__ dinvp,
                                                 unsigned short* __restrict__ C, int M) {
    constexpr int BK = 64;
    constexpr int MI = BM / 32;
    constexpr int WN = BN / 32;
    __shared__ unsigned short As[BM * BK];
    __shared__ unsigned short Bs[BN * BK];

    const int tid = threadIdx.x;
    const int wid = tid >> 6;
    const int lane16 = tid & 15;
    const int quad = (tid >> 4) & 3;
    const int wm = (wid >> 1) * (BM / 2);
    const int wn = (wid & 1) * (BN / 2);
    const int bm = blockIdx.x * BM;
    const int bn = blockIdx.y * BN;

    f32x4 acc[MI][WN];
    #pragma unroll
    for (int mi = 0; mi < MI; ++mi)
        #pragma unroll
        for (int ni = 0; ni < WN; ++ni) acc[mi][ni] = (f32x4)(0.f);

    for (int kt = 0; kt < K / BK; ++kt) {
        #pragma unroll
        for (int c = 0; c < (BM * 8) / 256; ++c) {
            int ch = tid + c * 256;
            int row = ch >> 3, kc = ch & 7;
            int gm = bm + row;
            u16x8 av = (u16x8)(0);
            if (gm < M) av = *reinterpret_cast<const u16x8*>(&A[(size_t)gm * K + kt * BK + kc * 8]);
            *reinterpret_cast<u16x8*>(&As[row * 64 + ((kc * 8) ^ ((row & 7) << 3))]) = av;
        }
        #pragma unroll
        for (int c = 0; c < (BN * 8) / 256; ++c) {
            int ch = tid + c * 256;
            int row = ch >> 3, kc = ch & 7;
            u16x8 bv = *reinterpret_cast<const u16x8*>(&WT[(size_t)(bn + row) * K + kt * BK + kc * 8]);
            *reinterpret_cast<u16x8*>(&Bs[row * 64 + ((kc * 8) ^ ((row & 7) << 3))]) = bv;
        }
        __syncthreads();

        #pragma unroll
        for (int ks = 0; ks < 2; ++ks) {
            f16x8 af[MI], bf[WN];
            #pragma unroll
            for (int mi = 0; mi < MI; ++mi) {
                int row = wm + mi * 16 + lane16;
                int kidx = ks * 32 + quad * 8;
                af[mi] = *reinterpret_cast<f16x8*>(&As[row * 64 + (kidx ^ ((row & 7) << 3))]);
            }
            #pragma unroll
            for (int ni = 0; ni < WN; ++ni) {
                int row = wn + ni * 16 + lane16;
                int kidx = ks * 32 + quad * 8;
                bf[ni] = *reinterpret_cast<f16x8*>(&Bs[row * 64 + (kidx ^ ((row & 7) << 3))]);
            }
            #pragma unroll
            for (int mi = 0; mi < MI; ++mi)
                #pragma unroll
                for (int ni = 0; ni < WN; ++ni)
                    acc[mi][ni] = __builtin_amdgcn_mfma_f32_16x16x32_f16(af[mi], bf[ni], acc[mi][ni], 0, 0, 0);
        }
        __syncthreads();
    }

    #pragma unroll
    for (int mi = 0; mi < MI; ++mi) {
        #pragma unroll
        for (int r = 0; r < 4; ++r) {
            int gm = bm + wm + mi * 16 + quad * 4 + r;
            if (gm >= M) continue;
            float sc = SCALE ? dinvp[gm] : 1.f;
            #pragma unroll
            for (int ni = 0; ni < WN; ++ni) {
                int gn = bn + wn + ni * 16 + lane16;
                float v = acc[mi][ni][r];
                if (BIAS) v += bias[gn];
                if (RELU) v = fmaxf(v, 0.f);
                if (SCALE) v *= sc;
                C[(size_t)gm * N + gn] = f2h(v);
            }
        }
    }
}

// pool stage 2 + final linear: 64 blocks x 128 threads.
__global__ void poolfinal_kernel(const float* __restrict__ partial,
                                 const int* __restrict__ gstart,
                                 const float* __restrict__ Wl, const float* __restrict__ bl,
                                 float* __restrict__ out) {
    __shared__ float2 red[128];
    int g = blockIdx.x, c = threadIdx.x;
    float s = 0.f;
    #pragma unroll
    for (int y = 0; y < 8; ++y) s += partial[(size_t)(g * 8 + y) * 128 + c];
    int cnt = gstart[g + 1] - gstart[g];
    if (cnt < 1) cnt = 1;
    float p = s / (float)cnt;
    red[c] = make_float2(p * Wl[c * 2 + 0], p * Wl[c * 2 + 1]);
    __syncthreads();
    for (int off = 64; off > 0; off >>= 1) {
        if (c < off) {
            red[c].x += red[c + off].x;
            red[c].y += red[c + off].y;
        }
        __syncthreads();
    }
    if (c == 0) {
        out[g * 2 + 0] = red[0].x + bl[0];
        out[g * 2 + 1] = red[0].y + bl[1];
    }
}

extern "C" void kernel_launch(void* const* d_in, const int* in_sizes, int n_in,
                              void* d_out, int out_size, void* d_ws, size_t ws_size,
                              hipStream_t stream) {
    const float* x   = (const float*)d_in[0];
    const int*   ei  = (const int*)d_in[1];
    const int*   bat = (const int*)d_in[2];
    const float* W1  = (const float*)d_in[3];
    const float* b1  = (const float*)d_in[4];
    const float* W2  = (const float*)d_in[5];
    const float* b2  = (const float*)d_in[6];
    const float* W3  = (const float*)d_in[7];
    const float* b3  = (const float*)d_in[8];
    const float* Wl  = (const float*)d_in[9];
    const float* bl  = (const float*)d_in[10];
    float* out = (float*)d_out;

    const int N = N_NODES_C;
    const int E = in_sizes[1] / 2;
    const int G = N_GRAPHS_C;

    const int* src = ei;
    const int* dst = ei + E;

    // -------- workspace layout --------
    unsigned short* xs  = (unsigned short*)d_ws;         // N*128 f16 (x*dinv)
    unsigned short* A1b = xs  + (size_t)N * 128;         // N*128
    unsigned short* H1  = A1b + (size_t)N * 128;         // N*512
    unsigned short* T2s = H1  + (size_t)N * 512;         // N*256 ((H1@W2)*dinv)
    unsigned short* H2  = T2s + (size_t)N * 256;         // N*256
    unsigned short* T3s = H2  + (size_t)N * 256;         // N*128 ((H2@W3)*dinv)
    unsigned short* W1T = T3s + (size_t)N * 128;         // 512*128 f16 [N][K]
    unsigned short* W2T = W1T + 512 * 128;               // 256*512
    unsigned short* W3T = W2T + 256 * 512;               // 128*256
    int*   deg_cnt = (int*)(W3T + 128 * 256);            // N
    int*   row_ptr = deg_cnt + N;                        // N+1
    int*   cursor  = row_ptr + (N + 1);                  // N
    int*   col_idx = cursor + N;                         // E
    float* dinv    = (float*)(col_idx + E);              // N
    int*   gstart  = (int*)(dinv + N);                   // G+1 (+pad)
    float* partial = (float*)(gstart + (G + 4));         // G*8*128 f32

    // --- setup ---
    hipMemsetAsync(deg_cnt, 0, N * sizeof(int), stream);
    {
        int total = E + 128 * 512 + 512 * 256 + 256 * 128 + N;
        prep_kernel<<<(total + 255) / 256, 256, 0, stream>>>(dst, deg_cnt, E,
                                                             W1, W2, W3, W1T, W2T, W3T,
                                                             bat, N, G, gstart);
    }
    scan_kernel<<<1, 1024, 0, stream>>>(deg_cnt, row_ptr, cursor, dinv, N);
    {
        int total = E + N * 32;
        fillx_kernel<<<(total + 255) / 256, 256, 0, stream>>>(src, dst, cursor, col_idx, E,
                                                              x, dinv, xs, N);
    }

    const int MB128 = (N + 127) / 128;   // 157
    const int MB64  = (N + 63) / 64;     // 313
    const int AGGB  = (N + 3) / 4;       // 5000 (one wave per node)

    // --- layer 1: A1 = Ahat x, H1 = relu(A1 @ W1 + b1) ---
    agg_kernel<128, false, false><<<AGGB, 256, 0, stream>>>(xs, dinv, row_ptr, col_idx, nullptr, A1b, N);
    {
        dim3 grid(MB128, 512 / 128);
        gemm_mfma<128, 512, 128, 128, true, true, false><<<grid, 256, 0, stream>>>(A1b, W1T, b1, nullptr, H1, N);
    }
    // --- layer 2: T2s = (H1 @ W2)*dinv, H2 = relu(dinv*(T2s_i + sum) + b2) ---
    {
        dim3 grid(MB64, 256 / 128);
        gemm_mfma<512, 256, 64, 128, false, false, true><<<grid, 256, 0, stream>>>(H1, W2T, nullptr, dinv, T2s, N);
    }
    agg_kernel<256, true, true><<<AGGB, 256, 0, stream>>>(T2s, dinv, row_ptr, col_idx, b2, H2, N);
    // --- layer 3: T3s = (H2 @ W3)*dinv, then agg3 fused into pool stage 1 ---
    {
        dim3 grid(MB64, 128 / 64);
        gemm_mfma<256, 128, 64, 64, false, false, true><<<grid, 256, 0, stream>>>(H2, W3T, nullptr, dinv, T3s, N);
    }
    {
        dim3 grid(G, 8);
        agg_pool_kernel<<<grid, 256, 0, stream>>>(T3s, dinv, row_ptr, col_idx, b3, gstart, partial);
    }

    // --- pool finish + final linear ---
    poolfinal_kernel<<<G, 128, 0, stream>>>(partial, gstart, Wl, bl, out);
}

// Round 12
// 156.861 us; speedup vs baseline: 1.0484x; 1.0484x over previous
//
#include <hip/hip_runtime.h>
#include <hip/hip_bf16.h>

// ---------------------------------------------------------------------------
// GCN: 3x gcn_conv + global_mean_pool + linear
//   h' = D^-1/2 (A+I) D^-1/2 (h W) + b
// Layer1 aggregates BEFORE GEMM ((AX)W == A(XW)), layers 2/3 after.
// dinv FOLDED into stored features; aggregation = pure gather+sum.
// F16 features + weights. Agg: ONE WAVE PER NODE, half-wave row gathers.
// GEMMs: LDS-staged f16 MFMA, XOR-swizzled, single weight plane.
// Pool: two-stage deterministic (R11 post-mortem: fusing agg3 into pool
// stage 1 cut gather parallelism 10x — 2048 waves vs 20000 — and regressed).
// Scan: 16-wave range-partitioned. 12 dispatches. (R10 configuration.)
// ---------------------------------------------------------------------------

#define N_NODES_C  20000
#define N_GRAPHS_C 64
#define HID_C      512

typedef __attribute__((ext_vector_type(8))) _Float16 f16x8;
typedef __attribute__((ext_vector_type(8))) unsigned short u16x8;
typedef __attribute__((ext_vector_type(4))) float f32x4;

static __device__ __forceinline__ unsigned short f2h(float f) {
    _Float16 h = (_Float16)f;
    return __builtin_bit_cast(unsigned short, h);
}
static __device__ __forceinline__ float h2f(unsigned short u) {
    return (float)__builtin_bit_cast(_Float16, u);
}
static __device__ __forceinline__ float hu_lo(unsigned u) {
    return (float)__builtin_bit_cast(_Float16, (unsigned short)(u & 0xffffu));
}
static __device__ __forceinline__ float hu_hi(unsigned u) {
    return (float)__builtin_bit_cast(_Float16, (unsigned short)(u >> 16));
}

// 16-wave range-partitioned scan
__global__ __launch_bounds__(1024) void scan_kernel(const int* __restrict__ deg_cnt,
                                                    int* __restrict__ row_ptr,
                                                    int* __restrict__ cursor,
                                                    float* __restrict__ dinv, int n) {
    __shared__ int ws[16];
    int t = threadIdx.x;
    int wid = t >> 6, lane = t & 63;
    const int RANGE = (n + 15) >> 4;
    const int ROUNDS = (RANGE + 63) >> 6;
    int base = wid * RANGE;

    int s = 0;
    for (int r = 0; r < ROUNDS; ++r) {
        int off = r * 64 + lane;
        int idx = base + off;
        if (off < RANGE && idx < n) s += deg_cnt[idx];
    }
    #pragma unroll
    for (int o = 32; o > 0; o >>= 1) s += __shfl_xor(s, o);
    if (lane == 0) ws[wid] = s;
    __syncthreads();

    int carry = 0;
    for (int j = 0; j < wid; ++j) carry += ws[j];

    for (int r = 0; r < ROUNDS; ++r) {
        int off = r * 64 + lane;
        int idx = base + off;
        int v = (off < RANGE && idx < n) ? deg_cnt[idx] : 0;
        int x = v;
        #pragma unroll
        for (int o = 1; o < 64; o <<= 1) {
            int y = __shfl_up(x, o);
            if (lane >= o) x += y;
        }
        if (off < RANGE && idx < n) {
            int rp = carry + x - v;
            row_ptr[idx] = rp;
            cursor[idx]  = rp;
            dinv[idx]    = rsqrtf((float)(v + 1));
        }
        carry += __shfl(x, 63);
    }
    if (t == 1023) row_ptr[n] = carry;
}

static __device__ __forceinline__ void wconv_body(const float* __restrict__ W, int i,
                                                  int Kd, int Nd,
                                                  unsigned short* __restrict__ WT) {
    int k = i / Nd, n = i % Nd;
    WT[(size_t)n * Kd + k] = f2h(W[i]);
}

// Fused setup: edge-count + 3x weight transpose (f16) + graph bounds.
__global__ void prep_kernel(const int* __restrict__ dst, int* __restrict__ deg_cnt, int E,
                            const float* __restrict__ W1, const float* __restrict__ W2,
                            const float* __restrict__ W3,
                            unsigned short* __restrict__ W1T,
                            unsigned short* __restrict__ W2T,
                            unsigned short* __restrict__ W3T,
                            const int* __restrict__ batch, int n, int ngraphs,
                            int* __restrict__ gstart) {
    int t = blockIdx.x * blockDim.x + threadIdx.x;
    if (t < E) {
        atomicAdd(&deg_cnt[dst[t]], 1);
        return;
    }
    t -= E;
    if (t < 128 * 512) { wconv_body(W1, t, 128, 512, W1T); return; }
    t -= 128 * 512;
    if (t < 512 * 256) { wconv_body(W2, t, 512, 256, W2T); return; }
    t -= 512 * 256;
    if (t < 256 * 128) { wconv_body(W3, t, 256, 128, W3T); return; }
    t -= 256 * 128;
    {
        int i = t;
        if (i >= n) return;
        int b = batch[i];
        if (i == 0) {
            for (int g = 0; g <= b; ++g) gstart[g] = 0;
        } else {
            int bp = batch[i - 1];
            if (bp != b) for (int g = bp + 1; g <= b; ++g) gstart[g] = i;
        }
        if (i == n - 1) {
            for (int g = b + 1; g <= ngraphs; ++g) gstart[g] = n;
        }
    }
}

// Fused: CSR fill (scatter) + xs = f16(x*dinv)
__global__ void fillx_kernel(const int* __restrict__ src, const int* __restrict__ dst,
                             int* __restrict__ cursor, int* __restrict__ col_idx, int E,
                             const float* __restrict__ x, const float* __restrict__ dinv,
                             unsigned short* __restrict__ xs, int nrows) {
    int t = blockIdx.x * blockDim.x + threadIdx.x;
    if (t < E) {
        int d = dst[t];
        int pos = atomicAdd(&cursor[d], 1);
        col_idx[pos] = src[t];
    } else {
        int u = t - E;
        int row = u >> 5, q = u & 31;
        if (row >= nrows) return;
        float di = dinv[row];
        f32x4 v = *reinterpret_cast<const f32x4*>(&x[(size_t)row * 128 + q * 4]);
        ushort4 o;
        o.x = f2h(v.x * di); o.y = f2h(v.y * di);
        o.z = f2h(v.z * di); o.w = f2h(v.w * di);
        *reinterpret_cast<ushort4*>(&xs[(size_t)row * 128 + q * 4]) = o;
    }
}

// ---------------------------------------------------------------------------
// Aggregation: out[i] = dinv[i]*(hs[i] + sum_{e in(i)} hs[src]) (+bias)(relu)
// ONE WAVE PER NODE (4 nodes/block). Half-wave: lanes 0-31 edge j, lanes
// 32-63 edge j+1; CPL f16/lane. Unroll 4 steps = 8 edges in flight.
// ---------------------------------------------------------------------------
template <int F, bool BIAS, bool RELU>
__global__ __launch_bounds__(256) void agg_kernel(const unsigned short* __restrict__ hs,
                                                  const float* __restrict__ dinv,
                                                  const int* __restrict__ row_ptr,
                                                  const int* __restrict__ col_idx,
                                                  const float* __restrict__ bias,
                                                  unsigned short* __restrict__ out, int n) {
    constexpr int CPL = F / 32;         // 4 (F=128) or 8 (F=256)
    int tid = threadIdx.x;
    int wid = tid >> 6, lane = tid & 63;
    int h = lane >> 5, l32 = lane & 31;
    int i = blockIdx.x * 4 + wid;
    if (i >= n) return;                 // wave-uniform; no barriers in kernel
    int e0 = row_ptr[i], e1 = row_ptr[i + 1];

    float acc[CPL];
    #pragma unroll
    for (int v = 0; v < CPL; ++v) acc[v] = 0.f;

    if (h == 0) {
        const unsigned short* p = &hs[(size_t)i * F + l32 * CPL];
        if constexpr (CPL == 4) {
            uint2 u = *reinterpret_cast<const uint2*>(p);
            acc[0] = hu_lo(u.x); acc[1] = hu_hi(u.x);
            acc[2] = hu_lo(u.y); acc[3] = hu_hi(u.y);
        } else {
            uint4 u = *reinterpret_cast<const uint4*>(p);
            acc[0] = hu_lo(u.x); acc[1] = hu_hi(u.x);
            acc[2] = hu_lo(u.y); acc[3] = hu_hi(u.y);
            acc[4] = hu_lo(u.z); acc[5] = hu_hi(u.z);
            acc[6] = hu_lo(u.w); acc[7] = hu_hi(u.w);
        }
    }

    for (int base = e0; base < e1; base += 64) {
        int rem = e1 - base;
        int mm = rem < 64 ? rem : 64;
        int myidx = col_idx[base + (lane < mm ? lane : 0)];
        for (int j0 = 0; j0 < mm; j0 += 8) {
            #pragma unroll
            for (int k = 0; k < 4; ++k) {
                int j = j0 + 2 * k + h;
                int jc = j < mm ? j : 0;
                int srcn = __shfl(myidx, jc);
                float w = (j < mm) ? 1.f : 0.f;
                const unsigned short* p = &hs[(size_t)srcn * F + l32 * CPL];
                if constexpr (CPL == 4) {
                    uint2 u = *reinterpret_cast<const uint2*>(p);
                    acc[0] = fmaf(hu_lo(u.x), w, acc[0]);
                    acc[1] = fmaf(hu_hi(u.x), w, acc[1]);
                    acc[2] = fmaf(hu_lo(u.y), w, acc[2]);
                    acc[3] = fmaf(hu_hi(u.y), w, acc[3]);
                } else {
                    uint4 u = *reinterpret_cast<const uint4*>(p);
                    acc[0] = fmaf(hu_lo(u.x), w, acc[0]);
                    acc[1] = fmaf(hu_hi(u.x), w, acc[1]);
                    acc[2] = fmaf(hu_lo(u.y), w, acc[2]);
                    acc[3] = fmaf(hu_hi(u.y), w, acc[3]);
                    acc[4] = fmaf(hu_lo(u.z), w, acc[4]);
                    acc[5] = fmaf(hu_hi(u.z), w, acc[5]);
                    acc[6] = fmaf(hu_lo(u.w), w, acc[6]);
                    acc[7] = fmaf(hu_hi(u.w), w, acc[7]);
                }
            }
        }
    }

    #pragma unroll
    for (int v = 0; v < CPL; ++v) acc[v] += __shfl_xor(acc[v], 32);

    if (h == 0) {
        float di = dinv[i];
        unsigned short ov[CPL];
        #pragma unroll
        for (int v = 0; v < CPL; ++v) {
            float r = di * acc[v];
            if (BIAS) r += bias[l32 * CPL + v];
            if (RELU) r = fmaxf(r, 0.f);
            ov[v] = f2h(r);
        }
        if constexpr (CPL == 4) {
            uint2 o;
            o.x = (unsigned)ov[0] | ((unsigned)ov[1] << 16);
            o.y = (unsigned)ov[2] | ((unsigned)ov[3] << 16);
            *reinterpret_cast<uint2*>(&out[(size_t)i * F + l32 * CPL]) = o;
        } else {
            uint4 o;
            o.x = (unsigned)ov[0] | ((unsigned)ov[1] << 16);
            o.y = (unsigned)ov[2] | ((unsigned)ov[3] << 16);
            o.z = (unsigned)ov[4] | ((unsigned)ov[5] << 16);
            o.w = (unsigned)ov[6] | ((unsigned)ov[7] << 16);
            *reinterpret_cast<uint4*>(&out[(size_t)i * F + l32 * CPL]) = o;
        }
    }
}

// ---------------------------------------------------------------------------
// MFMA f16 GEMM: C[M,N] = A[M,K] @ W[K,N] (+bias)(relu)(*dinv[row]) -> f16
// A [M][K] f16, WT [N][K] f16. BK=64, 256 threads = 4 waves (2x2).
// LDS XOR-swizzled (ushort units): idx = row*64 + (k ^ ((row&7)<<3))
// ---------------------------------------------------------------------------
template <int K, int N, int BM, int BN, bool BIAS, bool RELU, bool SCALE>
__global__ __launch_bounds__(256) void gemm_mfma(const unsigned short* __restrict__ A,
                                                 const unsigned short* __restrict__ WT,
                                                 const float* __restrict__ bias,
                                                 const float* __restrict__ dinvp,
                                                 unsigned short* __restrict__ C, int M) {
    constexpr int BK = 64;
    constexpr int MI = BM / 32;
    constexpr int WN = BN / 32;
    __shared__ unsigned short As[BM * BK];
    __shared__ unsigned short Bs[BN * BK];

    const int tid = threadIdx.x;
    const int wid = tid >> 6;
    const int lane16 = tid & 15;
    const int quad = (tid >> 4) & 3;
    const int wm = (wid >> 1) * (BM / 2);
    const int wn = (wid & 1) * (BN / 2);
    const int bm = blockIdx.x * BM;
    const int bn = blockIdx.y * BN;

    f32x4 acc[MI][WN];
    #pragma unroll
    for (int mi = 0; mi < MI; ++mi)
        #pragma unroll
        for (int ni = 0; ni < WN; ++ni) acc[mi][ni] = (f32x4)(0.f);

    for (int kt = 0; kt < K / BK; ++kt) {
        #pragma unroll
        for (int c = 0; c < (BM * 8) / 256; ++c) {
            int ch = tid + c * 256;
            int row = ch >> 3, kc = ch & 7;
            int gm = bm + row;
            u16x8 av = (u16x8)(0);
            if (gm < M) av = *reinterpret_cast<const u16x8*>(&A[(size_t)gm * K + kt * BK + kc * 8]);
            *reinterpret_cast<u16x8*>(&As[row * 64 + ((kc * 8) ^ ((row & 7) << 3))]) = av;
        }
        #pragma unroll
        for (int c = 0; c < (BN * 8) / 256; ++c) {
            int ch = tid + c * 256;
            int row = ch >> 3, kc = ch & 7;
            u16x8 bv = *reinterpret_cast<const u16x8*>(&WT[(size_t)(bn + row) * K + kt * BK + kc * 8]);
            *reinterpret_cast<u16x8*>(&Bs[row * 64 + ((kc * 8) ^ ((row & 7) << 3))]) = bv;
        }
        __syncthreads();

        #pragma unroll
        for (int ks = 0; ks < 2; ++ks) {
            f16x8 af[MI], bf[WN];
            #pragma unroll
            for (int mi = 0; mi < MI; ++mi) {
                int row = wm + mi * 16 + lane16;
                int kidx = ks * 32 + quad * 8;
                af[mi] = *reinterpret_cast<f16x8*>(&As[row * 64 + (kidx ^ ((row & 7) << 3))]);
            }
            #pragma unroll
            for (int ni = 0; ni < WN; ++ni) {
                int row = wn + ni * 16 + lane16;
                int kidx = ks * 32 + quad * 8;
                bf[ni] = *reinterpret_cast<f16x8*>(&Bs[row * 64 + (kidx ^ ((row & 7) << 3))]);
            }
            #pragma unroll
            for (int mi = 0; mi < MI; ++mi)
                #pragma unroll
                for (int ni = 0; ni < WN; ++ni)
                    acc[mi][ni] = __builtin_amdgcn_mfma_f32_16x16x32_f16(af[mi], bf[ni], acc[mi][ni], 0, 0, 0);
        }
        __syncthreads();
    }

    #pragma unroll
    for (int mi = 0; mi < MI; ++mi) {
        #pragma unroll
        for (int r = 0; r < 4; ++r) {
            int gm = bm + wm + mi * 16 + quad * 4 + r;
            if (gm >= M) continue;
            float sc = SCALE ? dinvp[gm] : 1.f;
            #pragma unroll
            for (int ni = 0; ni < WN; ++ni) {
                int gn = bn + wn + ni * 16 + lane16;
                float v = acc[mi][ni][r];
                if (BIAS) v += bias[gn];
                if (RELU) v = fmaxf(v, 0.f);
                if (SCALE) v *= sc;
                C[(size_t)gm * N + gn] = f2h(v);
            }
        }
    }
}

// pool stage 1: grid (G, 8), 256 threads = 2 rows x 128 cols, rows strided by 16
__global__ void pool_partial_kernel(const unsigned short* __restrict__ A,
                                    const int* __restrict__ gstart,
                                    float* __restrict__ partial) {
    __shared__ float sd[256];
    int g = blockIdx.x, y = blockIdx.y;
    int t = threadIdx.x;
    int c = t & 127, r = t >> 7;
    int s0 = gstart[g], s1 = gstart[g + 1];
    float s = 0.f;
    for (int i = s0 + y * 2 + r; i < s1; i += 16)
        s += h2f(A[(size_t)i * 128 + c]);
    sd[t] = s;
    __syncthreads();
    if (t < 128) partial[(size_t)(g * 8 + y) * 128 + c] = sd[t] + sd[t + 128];
}

// pool stage 2 + final linear: 64 blocks x 128 threads.
__global__ void poolfinal_kernel(const float* __restrict__ partial,
                                 const int* __restrict__ gstart,
                                 const float* __restrict__ Wl, const float* __restrict__ bl,
                                 float* __restrict__ out) {
    __shared__ float2 red[128];
    int g = blockIdx.x, c = threadIdx.x;
    float s = 0.f;
    #pragma unroll
    for (int y = 0; y < 8; ++y) s += partial[(size_t)(g * 8 + y) * 128 + c];
    int cnt = gstart[g + 1] - gstart[g];
    if (cnt < 1) cnt = 1;
    float p = s / (float)cnt;
    red[c] = make_float2(p * Wl[c * 2 + 0], p * Wl[c * 2 + 1]);
    __syncthreads();
    for (int off = 64; off > 0; off >>= 1) {
        if (c < off) {
            red[c].x += red[c + off].x;
            red[c].y += red[c + off].y;
        }
        __syncthreads();
    }
    if (c == 0) {
        out[g * 2 + 0] = red[0].x + bl[0];
        out[g * 2 + 1] = red[0].y + bl[1];
    }
}

extern "C" void kernel_launch(void* const* d_in, const int* in_sizes, int n_in,
                              void* d_out, int out_size, void* d_ws, size_t ws_size,
                              hipStream_t stream) {
    const float* x   = (const float*)d_in[0];
    const int*   ei  = (const int*)d_in[1];
    const int*   bat = (const int*)d_in[2];
    const float* W1  = (const float*)d_in[3];
    const float* b1  = (const float*)d_in[4];
    const float* W2  = (const float*)d_in[5];
    const float* b2  = (const float*)d_in[6];
    const float* W3  = (const float*)d_in[7];
    const float* b3  = (const float*)d_in[8];
    const float* Wl  = (const float*)d_in[9];
    const float* bl  = (const float*)d_in[10];
    float* out = (float*)d_out;

    const int N = N_NODES_C;
    const int E = in_sizes[1] / 2;
    const int G = N_GRAPHS_C;

    const int* src = ei;
    const int* dst = ei + E;

    // -------- workspace layout --------
    unsigned short* xs  = (unsigned short*)d_ws;         // N*128 f16 (x*dinv)
    unsigned short* A1b = xs  + (size_t)N * 128;         // N*128
    unsigned short* H1  = A1b + (size_t)N * 128;         // N*512
    unsigned short* T2s = H1  + (size_t)N * 512;         // N*256 ((H1@W2)*dinv)
    unsigned short* H2  = T2s + (size_t)N * 256;         // N*256
    unsigned short* T3s = H2  + (size_t)N * 256;         // N*128 ((H2@W3)*dinv)
    unsigned short* A3  = T3s + (size_t)N * 128;         // N*128
    unsigned short* W1T = A3  + (size_t)N * 128;         // 512*128 f16 [N][K]
    unsigned short* W2T = W1T + 512 * 128;               // 256*512
    unsigned short* W3T = W2T + 256 * 512;               // 128*256
    int*   deg_cnt = (int*)(W3T + 128 * 256);            // N
    int*   row_ptr = deg_cnt + N;                        // N+1
    int*   cursor  = row_ptr + (N + 1);                  // N
    int*   col_idx = cursor + N;                         // E
    float* dinv    = (float*)(col_idx + E);              // N
    int*   gstart  = (int*)(dinv + N);                   // G+1 (+pad)
    float* partial = (float*)(gstart + (G + 4));         // G*8*128 f32

    // --- setup ---
    hipMemsetAsync(deg_cnt, 0, N * sizeof(int), stream);
    {
        int total = E + 128 * 512 + 512 * 256 + 256 * 128 + N;
        prep_kernel<<<(total + 255) / 256, 256, 0, stream>>>(dst, deg_cnt, E,
                                                             W1, W2, W3, W1T, W2T, W3T,
                                                             bat, N, G, gstart);
    }
    scan_kernel<<<1, 1024, 0, stream>>>(deg_cnt, row_ptr, cursor, dinv, N);
    {
        int total = E + N * 32;
        fillx_kernel<<<(total + 255) / 256, 256, 0, stream>>>(src, dst, cursor, col_idx, E,
                                                              x, dinv, xs, N);
    }

    const int MB128 = (N + 127) / 128;   // 157
    const int MB64  = (N + 63) / 64;     // 313
    const int AGGB  = (N + 3) / 4;       // 5000 (one wave per node)

    // --- layer 1: A1 = Ahat x, H1 = relu(A1 @ W1 + b1) ---
    agg_kernel<128, false, false><<<AGGB, 256, 0, stream>>>(xs, dinv, row_ptr, col_idx, nullptr, A1b, N);
    {
        dim3 grid(MB128, 512 / 128);
        gemm_mfma<128, 512, 128, 128, true, true, false><<<grid, 256, 0, stream>>>(A1b, W1T, b1, nullptr, H1, N);
    }
    // --- layer 2: T2s = (H1 @ W2)*dinv, H2 = relu(dinv*(T2s_i + sum) + b2) ---
    {
        dim3 grid(MB64, 256 / 128);
        gemm_mfma<512, 256, 64, 128, false, false, true><<<grid, 256, 0, stream>>>(H1, W2T, nullptr, dinv, T2s, N);
    }
    agg_kernel<256, true, true><<<AGGB, 256, 0, stream>>>(T2s, dinv, row_ptr, col_idx, b2, H2, N);
    // --- layer 3: T3s = (H2 @ W3)*dinv, A3 = dinv*(T3s_i + sum) + b3 ---
    {
        dim3 grid(MB64, 128 / 64);
        gemm_mfma<256, 128, 64, 64, false, false, true><<<grid, 256, 0, stream>>>(H2, W3T, nullptr, dinv, T3s, N);
    }
    agg_kernel<128, true, false><<<AGGB, 256, 0, stream>>>(T3s, dinv, row_ptr, col_idx, b3, A3, N);

    // --- pool (two-stage) + final linear ---
    {
        dim3 grid(G, 8);
        pool_partial_kernel<<<grid, 256, 0, stream>>>(A3, gstart, partial);
    }
    poolfinal_kernel<<<G, 128, 0, stream>>>(partial, gstart, Wl, bl, out);
}

// Round 13
// 156.269 us; speedup vs baseline: 1.0524x; 1.0038x over previous
//
#include <hip/hip_runtime.h>
#include <hip/hip_bf16.h>

// ---------------------------------------------------------------------------
// GCN: 3x gcn_conv + global_mean_pool + linear
//   h' = D^-1/2 (A+I) D^-1/2 (h W) + b
// Layer1 aggregates BEFORE GEMM ((AX)W == A(XW)), layers 2/3 after.
// dinv FOLDED into stored features; aggregation = pure gather+sum.
// F16 features + weights. Agg: ONE WAVE PER NODE, half-wave row gathers.
// GEMMs: LDS-staged f16 MFMA, XOR-swizzled, single weight plane.
// Pool: two-stage deterministic. Scan: 16-wave range-partitioned.
// R13: custom zero_kernel replaces hipMemsetAsync(deg_cnt) — the runtime's
// fillBufferAligned for that 80KB memset measured 41us/replay (26% of total).
// ---------------------------------------------------------------------------

#define N_NODES_C  20000
#define N_GRAPHS_C 64
#define HID_C      512

typedef __attribute__((ext_vector_type(8))) _Float16 f16x8;
typedef __attribute__((ext_vector_type(8))) unsigned short u16x8;
typedef __attribute__((ext_vector_type(4))) float f32x4;

static __device__ __forceinline__ unsigned short f2h(float f) {
    _Float16 h = (_Float16)f;
    return __builtin_bit_cast(unsigned short, h);
}
static __device__ __forceinline__ float h2f(unsigned short u) {
    return (float)__builtin_bit_cast(_Float16, u);
}
static __device__ __forceinline__ float hu_lo(unsigned u) {
    return (float)__builtin_bit_cast(_Float16, (unsigned short)(u & 0xffffu));
}
static __device__ __forceinline__ float hu_hi(unsigned u) {
    return (float)__builtin_bit_cast(_Float16, (unsigned short)(u >> 16));
}

// custom zero (replaces hipMemsetAsync's 41us fillBufferAligned)
__global__ void zero_kernel(int* __restrict__ p, int n) {
    int i = blockIdx.x * blockDim.x + threadIdx.x;
    if (i < n) p[i] = 0;
}

// 16-wave range-partitioned scan
__global__ __launch_bounds__(1024) void scan_kernel(const int* __restrict__ deg_cnt,
                                                    int* __restrict__ row_ptr,
                                                    int* __restrict__ cursor,
                                                    float* __restrict__ dinv, int n) {
    __shared__ int ws[16];
    int t = threadIdx.x;
    int wid = t >> 6, lane = t & 63;
    const int RANGE = (n + 15) >> 4;
    const int ROUNDS = (RANGE + 63) >> 6;
    int base = wid * RANGE;

    int s = 0;
    for (int r = 0; r < ROUNDS; ++r) {
        int off = r * 64 + lane;
        int idx = base + off;
        if (off < RANGE && idx < n) s += deg_cnt[idx];
    }
    #pragma unroll
    for (int o = 32; o > 0; o >>= 1) s += __shfl_xor(s, o);
    if (lane == 0) ws[wid] = s;
    __syncthreads();

    int carry = 0;
    for (int j = 0; j < wid; ++j) carry += ws[j];

    for (int r = 0; r < ROUNDS; ++r) {
        int off = r * 64 + lane;
        int idx = base + off;
        int v = (off < RANGE && idx < n) ? deg_cnt[idx] : 0;
        int x = v;
        #pragma unroll
        for (int o = 1; o < 64; o <<= 1) {
            int y = __shfl_up(x, o);
            if (lane >= o) x += y;
        }
        if (off < RANGE && idx < n) {
            int rp = carry + x - v;
            row_ptr[idx] = rp;
            cursor[idx]  = rp;
            dinv[idx]    = rsqrtf((float)(v + 1));
        }
        carry += __shfl(x, 63);
    }
    if (t == 1023) row_ptr[n] = carry;
}

static __device__ __forceinline__ void wconv_body(const float* __restrict__ W, int i,
                                                  int Kd, int Nd,
                                                  unsigned short* __restrict__ WT) {
    int k = i / Nd, n = i % Nd;
    WT[(size_t)n * Kd + k] = f2h(W[i]);
}

// Fused setup: edge-count + 3x weight transpose (f16) + graph bounds.
__global__ void prep_kernel(const int* __restrict__ dst, int* __restrict__ deg_cnt, int E,
                            const float* __restrict__ W1, const float* __restrict__ W2,
                            const float* __restrict__ W3,
                            unsigned short* __restrict__ W1T,
                            unsigned short* __restrict__ W2T,
                            unsigned short* __restrict__ W3T,
                            const int* __restrict__ batch, int n, int ngraphs,
                            int* __restrict__ gstart) {
    int t = blockIdx.x * blockDim.x + threadIdx.x;
    if (t < E) {
        atomicAdd(&deg_cnt[dst[t]], 1);
        return;
    }
    t -= E;
    if (t < 128 * 512) { wconv_body(W1, t, 128, 512, W1T); return; }
    t -= 128 * 512;
    if (t < 512 * 256) { wconv_body(W2, t, 512, 256, W2T); return; }
    t -= 512 * 256;
    if (t < 256 * 128) { wconv_body(W3, t, 256, 128, W3T); return; }
    t -= 256 * 128;
    {
        int i = t;
        if (i >= n) return;
        int b = batch[i];
        if (i == 0) {
            for (int g = 0; g <= b; ++g) gstart[g] = 0;
        } else {
            int bp = batch[i - 1];
            if (bp != b) for (int g = bp + 1; g <= b; ++g) gstart[g] = i;
        }
        if (i == n - 1) {
            for (int g = b + 1; g <= ngraphs; ++g) gstart[g] = n;
        }
    }
}

// Fused: CSR fill (scatter) + xs = f16(x*dinv)
__global__ void fillx_kernel(const int* __restrict__ src, const int* __restrict__ dst,
                             int* __restrict__ cursor, int* __restrict__ col_idx, int E,
                             const float* __restrict__ x, const float* __restrict__ dinv,
                             unsigned short* __restrict__ xs, int nrows) {
    int t = blockIdx.x * blockDim.x + threadIdx.x;
    if (t < E) {
        int d = dst[t];
        int pos = atomicAdd(&cursor[d], 1);
        col_idx[pos] = src[t];
    } else {
        int u = t - E;
        int row = u >> 5, q = u & 31;
        if (row >= nrows) return;
        float di = dinv[row];
        f32x4 v = *reinterpret_cast<const f32x4*>(&x[(size_t)row * 128 + q * 4]);
        ushort4 o;
        o.x = f2h(v.x * di); o.y = f2h(v.y * di);
        o.z = f2h(v.z * di); o.w = f2h(v.w * di);
        *reinterpret_cast<ushort4*>(&xs[(size_t)row * 128 + q * 4]) = o;
    }
}

// ---------------------------------------------------------------------------
// Aggregation: out[i] = dinv[i]*(hs[i] + sum_{e in(i)} hs[src]) (+bias)(relu)
// ONE WAVE PER NODE (4 nodes/block). Half-wave: lanes 0-31 edge j, lanes
// 32-63 edge j+1; CPL f16/lane. Unroll 4 steps = 8 edges in flight.
// ---------------------------------------------------------------------------
template <int F, bool BIAS, bool RELU>
__global__ __launch_bounds__(256) void agg_kernel(const unsigned short* __restrict__ hs,
                                                  const float* __restrict__ dinv,
                                                  const int* __restrict__ row_ptr,
                                                  const int* __restrict__ col_idx,
                                                  const float* __restrict__ bias,
                                                  unsigned short* __restrict__ out, int n) {
    constexpr int CPL = F / 32;         // 4 (F=128) or 8 (F=256)
    int tid = threadIdx.x;
    int wid = tid >> 6, lane = tid & 63;
    int h = lane >> 5, l32 = lane & 31;
    int i = blockIdx.x * 4 + wid;
    if (i >= n) return;                 // wave-uniform; no barriers in kernel
    int e0 = row_ptr[i], e1 = row_ptr[i + 1];

    float acc[CPL];
    #pragma unroll
    for (int v = 0; v < CPL; ++v) acc[v] = 0.f;

    if (h == 0) {
        const unsigned short* p = &hs[(size_t)i * F + l32 * CPL];
        if constexpr (CPL == 4) {
            uint2 u = *reinterpret_cast<const uint2*>(p);
            acc[0] = hu_lo(u.x); acc[1] = hu_hi(u.x);
            acc[2] = hu_lo(u.y); acc[3] = hu_hi(u.y);
        } else {
            uint4 u = *reinterpret_cast<const uint4*>(p);
            acc[0] = hu_lo(u.x); acc[1] = hu_hi(u.x);
            acc[2] = hu_lo(u.y); acc[3] = hu_hi(u.y);
            acc[4] = hu_lo(u.z); acc[5] = hu_hi(u.z);
            acc[6] = hu_lo(u.w); acc[7] = hu_hi(u.w);
        }
    }

    for (int base = e0; base < e1; base += 64) {
        int rem = e1 - base;
        int mm = rem < 64 ? rem : 64;
        int myidx = col_idx[base + (lane < mm ? lane : 0)];
        for (int j0 = 0; j0 < mm; j0 += 8) {
            #pragma unroll
            for (int k = 0; k < 4; ++k) {
                int j = j0 + 2 * k + h;
                int jc = j < mm ? j : 0;
                int srcn = __shfl(myidx, jc);
                float w = (j < mm) ? 1.f : 0.f;
                const unsigned short* p = &hs[(size_t)srcn * F + l32 * CPL];
                if constexpr (CPL == 4) {
                    uint2 u = *reinterpret_cast<const uint2*>(p);
                    acc[0] = fmaf(hu_lo(u.x), w, acc[0]);
                    acc[1] = fmaf(hu_hi(u.x), w, acc[1]);
                    acc[2] = fmaf(hu_lo(u.y), w, acc[2]);
                    acc[3] = fmaf(hu_hi(u.y), w, acc[3]);
                } else {
                    uint4 u = *reinterpret_cast<const uint4*>(p);
                    acc[0] = fmaf(hu_lo(u.x), w, acc[0]);
                    acc[1] = fmaf(hu_hi(u.x), w, acc[1]);
                    acc[2] = fmaf(hu_lo(u.y), w, acc[2]);
                    acc[3] = fmaf(hu_hi(u.y), w, acc[3]);
                    acc[4] = fmaf(hu_lo(u.z), w, acc[4]);
                    acc[5] = fmaf(hu_hi(u.z), w, acc[5]);
                    acc[6] = fmaf(hu_lo(u.w), w, acc[6]);
                    acc[7] = fmaf(hu_hi(u.w), w, acc[7]);
                }
            }
        }
    }

    #pragma unroll
    for (int v = 0; v < CPL; ++v) acc[v] += __shfl_xor(acc[v], 32);

    if (h == 0) {
        float di = dinv[i];
        unsigned short ov[CPL];
        #pragma unroll
        for (int v = 0; v < CPL; ++v) {
            float r = di * acc[v];
            if (BIAS) r += bias[l32 * CPL + v];
            if (RELU) r = fmaxf(r, 0.f);
            ov[v] = f2h(r);
        }
        if constexpr (CPL == 4) {
            uint2 o;
            o.x = (unsigned)ov[0] | ((unsigned)ov[1] << 16);
            o.y = (unsigned)ov[2] | ((unsigned)ov[3] << 16);
            *reinterpret_cast<uint2*>(&out[(size_t)i * F + l32 * CPL]) = o;
        } else {
            uint4 o;
            o.x = (unsigned)ov[0] | ((unsigned)ov[1] << 16);
            o.y = (unsigned)ov[2] | ((unsigned)ov[3] << 16);
            o.z = (unsigned)ov[4] | ((unsigned)ov[5] << 16);
            o.w = (unsigned)ov[6] | ((unsigned)ov[7] << 16);
            *reinterpret_cast<uint4*>(&out[(size_t)i * F + l32 * CPL]) = o;
        }
    }
}

// ---------------------------------------------------------------------------
// MFMA f16 GEMM: C[M,N] = A[M,K] @ W[K,N] (+bias)(relu)(*dinv[row]) -> f16
// A [M][K] f16, WT [N][K] f16. BK=64, 256 threads = 4 waves (2x2).
// LDS XOR-swizzled (ushort units): idx = row*64 + (k ^ ((row&7)<<3))
// ---------------------------------------------------------------------------
template <int K, int N, int BM, int BN, bool BIAS, bool RELU, bool SCALE>
__global__ __launch_bounds__(256) void gemm_mfma(const unsigned short* __restrict__ A,
                                                 const unsigned short* __restrict__ WT,
                                                 const float* __restrict__ bias,
                                                 const float* __restrict__ dinvp,
                                                 unsigned short* __restrict__ C, int M) {
    constexpr int BK = 64;
    constexpr int MI = BM / 32;
    constexpr int WN = BN / 32;
    __shared__ unsigned short As[BM * BK];
    __shared__ unsigned short Bs[BN * BK];

    const int tid = threadIdx.x;
    const int wid = tid >> 6;
    const int lane16 = tid & 15;
    const int quad = (tid >> 4) & 3;
    const int wm = (wid >> 1) * (BM / 2);
    const int wn = (wid & 1) * (BN / 2);
    const int bm = blockIdx.x * BM;
    const int bn = blockIdx.y * BN;

    f32x4 acc[MI][WN];
    #pragma unroll
    for (int mi = 0; mi < MI; ++mi)
        #pragma unroll
        for (int ni = 0; ni < WN; ++ni) acc[mi][ni] = (f32x4)(0.f);

    for (int kt = 0; kt < K / BK; ++kt) {
        #pragma unroll
        for (int c = 0; c < (BM * 8) / 256; ++c) {
            int ch = tid + c * 256;
            int row = ch >> 3, kc = ch & 7;
            int gm = bm + row;
            u16x8 av = (u16x8)(0);
            if (gm < M) av = *reinterpret_cast<const u16x8*>(&A[(size_t)gm * K + kt * BK + kc * 8]);
            *reinterpret_cast<u16x8*>(&As[row * 64 + ((kc * 8) ^ ((row & 7) << 3))]) = av;
        }
        #pragma unroll
        for (int c = 0; c < (BN * 8) / 256; ++c) {
            int ch = tid + c * 256;
            int row = ch >> 3, kc = ch & 7;
            u16x8 bv = *reinterpret_cast<const u16x8*>(&WT[(size_t)(bn + row) * K + kt * BK + kc * 8]);
            *reinterpret_cast<u16x8*>(&Bs[row * 64 + ((kc * 8) ^ ((row & 7) << 3))]) = bv;
        }
        __syncthreads();

        #pragma unroll
        for (int ks = 0; ks < 2; ++ks) {
            f16x8 af[MI], bf[WN];
            #pragma unroll
            for (int mi = 0; mi < MI; ++mi) {
                int row = wm + mi * 16 + lane16;
                int kidx = ks * 32 + quad * 8;
                af[mi] = *reinterpret_cast<f16x8*>(&As[row * 64 + (kidx ^ ((row & 7) << 3))]);
            }
            #pragma unroll
            for (int ni = 0; ni < WN; ++ni) {
                int row = wn + ni * 16 + lane16;
                int kidx = ks * 32 + quad * 8;
                bf[ni] = *reinterpret_cast<f16x8*>(&Bs[row * 64 + (kidx ^ ((row & 7) << 3))]);
            }
            #pragma unroll
            for (int mi = 0; mi < MI; ++mi)
                #pragma unroll
                for (int ni = 0; ni < WN; ++ni)
                    acc[mi][ni] = __builtin_amdgcn_mfma_f32_16x16x32_f16(af[mi], bf[ni], acc[mi][ni], 0, 0, 0);
        }
        __syncthreads();
    }

    #pragma unroll
    for (int mi = 0; mi < MI; ++mi) {
        #pragma unroll
        for (int r = 0; r < 4; ++r) {
            int gm = bm + wm + mi * 16 + quad * 4 + r;
            if (gm >= M) continue;
            float sc = SCALE ? dinvp[gm] : 1.f;
            #pragma unroll
            for (int ni = 0; ni < WN; ++ni) {
                int gn = bn + wn + ni * 16 + lane16;
                float v = acc[mi][ni][r];
                if (BIAS) v += bias[gn];
                if (RELU) v = fmaxf(v, 0.f);
                if (SCALE) v *= sc;
                C[(size_t)gm * N + gn] = f2h(v);
            }
        }
    }
}

// pool stage 1: grid (G, 8), 256 threads = 2 rows x 128 cols, rows strided by 16
__global__ void pool_partial_kernel(const unsigned short* __restrict__ A,
                                    const int* __restrict__ gstart,
                                    float* __restrict__ partial) {
    __shared__ float sd[256];
    int g = blockIdx.x, y = blockIdx.y;
    int t = threadIdx.x;
    int c = t & 127, r = t >> 7;
    int s0 = gstart[g], s1 = gstart[g + 1];
    float s = 0.f;
    for (int i = s0 + y * 2 + r; i < s1; i += 16)
        s += h2f(A[(size_t)i * 128 + c]);
    sd[t] = s;
    __syncthreads();
    if (t < 128) partial[(size_t)(g * 8 + y) * 128 + c] = sd[t] + sd[t + 128];
}

// pool stage 2 + final linear: 64 blocks x 128 threads.
__global__ void poolfinal_kernel(const float* __restrict__ partial,
                                 const int* __restrict__ gstart,
                                 const float* __restrict__ Wl, const float* __restrict__ bl,
                                 float* __restrict__ out) {
    __shared__ float2 red[128];
    int g = blockIdx.x, c = threadIdx.x;
    float s = 0.f;
    #pragma unroll
    for (int y = 0; y < 8; ++y) s += partial[(size_t)(g * 8 + y) * 128 + c];
    int cnt = gstart[g + 1] - gstart[g];
    if (cnt < 1) cnt = 1;
    float p = s / (float)cnt;
    red[c] = make_float2(p * Wl[c * 2 + 0], p * Wl[c * 2 + 1]);
    __syncthreads();
    for (int off = 64; off > 0; off >>= 1) {
        if (c < off) {
            red[c].x += red[c + off].x;
            red[c].y += red[c + off].y;
        }
        __syncthreads();
    }
    if (c == 0) {
        out[g * 2 + 0] = red[0].x + bl[0];
        out[g * 2 + 1] = red[0].y + bl[1];
    }
}

extern "C" void kernel_launch(void* const* d_in, const int* in_sizes, int n_in,
                              void* d_out, int out_size, void* d_ws, size_t ws_size,
                              hipStream_t stream) {
    const float* x   = (const float*)d_in[0];
    const int*   ei  = (const int*)d_in[1];
    const int*   bat = (const int*)d_in[2];
    const float* W1  = (const float*)d_in[3];
    const float* b1  = (const float*)d_in[4];
    const float* W2  = (const float*)d_in[5];
    const float* b2  = (const float*)d_in[6];
    const float* W3  = (const float*)d_in[7];
    const float* b3  = (const float*)d_in[8];
    const float* Wl  = (const float*)d_in[9];
    const float* bl  = (const float*)d_in[10];
    float* out = (float*)d_out;

    const int N = N_NODES_C;
    const int E = in_sizes[1] / 2;
    const int G = N_GRAPHS_C;

    const int* src = ei;
    const int* dst = ei + E;

    // -------- workspace layout --------
    unsigned short* xs  = (unsigned short*)d_ws;         // N*128 f16 (x*dinv)
    unsigned short* A1b = xs  + (size_t)N * 128;         // N*128
    unsigned short* H1  = A1b + (size_t)N * 128;         // N*512
    unsigned short* T2s = H1  + (size_t)N * 512;         // N*256 ((H1@W2)*dinv)
    unsigned short* H2  = T2s + (size_t)N * 256;         // N*256
    unsigned short* T3s = H2  + (size_t)N * 256;         // N*128 ((H2@W3)*dinv)
    unsigned short* A3  = T3s + (size_t)N * 128;         // N*128
    unsigned short* W1T = A3  + (size_t)N * 128;         // 512*128 f16 [N][K]
    unsigned short* W2T = W1T + 512 * 128;               // 256*512
    unsigned short* W3T = W2T + 256 * 512;               // 128*256
    int*   deg_cnt = (int*)(W3T + 128 * 256);            // N
    int*   row_ptr = deg_cnt + N;                        // N+1
    int*   cursor  = row_ptr + (N + 1);                  // N
    int*   col_idx = cursor + N;                         // E
    float* dinv    = (float*)(col_idx + E);              // N
    int*   gstart  = (int*)(dinv + N);                   // G+1 (+pad)
    float* partial = (float*)(gstart + (G + 4));         // G*8*128 f32

    // --- setup ---
    zero_kernel<<<(N + 255) / 256, 256, 0, stream>>>(deg_cnt, N);
    {
        int total = E + 128 * 512 + 512 * 256 + 256 * 128 + N;
        prep_kernel<<<(total + 255) / 256, 256, 0, stream>>>(dst, deg_cnt, E,
                                                             W1, W2, W3, W1T, W2T, W3T,
                                                             bat, N, G, gstart);
    }
    scan_kernel<<<1, 1024, 0, stream>>>(deg_cnt, row_ptr, cursor, dinv, N);
    {
        int total = E + N * 32;
        fillx_kernel<<<(total + 255) / 256, 256, 0, stream>>>(src, dst, cursor, col_idx, E,
                                                              x, dinv, xs, N);
    }

    const int MB128 = (N + 127) / 128;   // 157
    const int MB64  = (N + 63) / 64;     // 313
    const int AGGB  = (N + 3) / 4;       // 5000 (one wave per node)

    // --- layer 1: A1 = Ahat x, H1 = relu(A1 @ W1 + b1) ---
    agg_kernel<128, false, false><<<AGGB, 256, 0, stream>>>(xs, dinv, row_ptr, col_idx, nullptr, A1b, N);
    {
        dim3 grid(MB128, 512 / 128);
        gemm_mfma<128, 512, 128, 128, true, true, false><<<grid, 256, 0, stream>>>(A1b, W1T, b1, nullptr, H1, N);
    }
    // --- layer 2: T2s = (H1 @ W2)*dinv, H2 = relu(dinv*(T2s_i + sum) + b2) ---
    {
        dim3 grid(MB64, 256 / 128);
        gemm_mfma<512, 256, 64, 128, false, false, true><<<grid, 256, 0, stream>>>(H1, W2T, nullptr, dinv, T2s, N);
    }
    agg_kernel<256, true, true><<<AGGB, 256, 0, stream>>>(T2s, dinv, row_ptr, col_idx, b2, H2, N);
    // --- layer 3: T3s = (H2 @ W3)*dinv, A3 = dinv*(T3s_i + sum) + b3 ---
    {
        dim3 grid(MB64, 128 / 64);
        gemm_mfma<256, 128, 64, 64, false, false, true><<<grid, 256, 0, stream>>>(H2, W3T, nullptr, dinv, T3s, N);
    }
    agg_kernel<128, true, false><<<AGGB, 256, 0, stream>>>(T3s, dinv, row_ptr, col_idx, b3, A3, N);

    // --- pool (two-stage) + final linear ---
    {
        dim3 grid(G, 8);
        pool_partial_kernel<<<grid, 256, 0, stream>>>(A3, gstart, partial);
    }
    poolfinal_kernel<<<G, 128, 0, stream>>>(partial, gstart, Wl, bl, out);
}

// Round 14
// 155.121 us; speedup vs baseline: 1.0602x; 1.0074x over previous
//
#include <hip/hip_runtime.h>
#include <hip/hip_bf16.h>

// ---------------------------------------------------------------------------
// GCN: 3x gcn_conv + global_mean_pool + linear
//   h' = D^-1/2 (A+I) D^-1/2 (h W) + b
// Layer1 aggregates BEFORE GEMM ((AX)W == A(XW)), layers 2/3 after.
// dinv FOLDED into stored features; aggregation = pure gather+sum.
// F16 features + weights. Agg: ONE WAVE PER NODE; EL-lane edge groups
// (EL=16 for F=128 -> 4 edges/step, EL=32 for F=256 -> 2 edges/step),
// 16B/lane uint4 gathers, unroll 4 -> 8-16 edges in flight.
// GEMMs: LDS-staged f16 MFMA, XOR-swizzled, single weight plane.
// Pool: two-stage deterministic. Scan: 16-wave range-partitioned.
// ---------------------------------------------------------------------------

#define N_NODES_C  20000
#define N_GRAPHS_C 64
#define HID_C      512

typedef __attribute__((ext_vector_type(8))) _Float16 f16x8;
typedef __attribute__((ext_vector_type(8))) unsigned short u16x8;
typedef __attribute__((ext_vector_type(4))) float f32x4;

static __device__ __forceinline__ unsigned short f2h(float f) {
    _Float16 h = (_Float16)f;
    return __builtin_bit_cast(unsigned short, h);
}
static __device__ __forceinline__ float h2f(unsigned short u) {
    return (float)__builtin_bit_cast(_Float16, u);
}
static __device__ __forceinline__ float hu_lo(unsigned u) {
    return (float)__builtin_bit_cast(_Float16, (unsigned short)(u & 0xffffu));
}
static __device__ __forceinline__ float hu_hi(unsigned u) {
    return (float)__builtin_bit_cast(_Float16, (unsigned short)(u >> 16));
}

// custom zero for deg_cnt
__global__ void zero_kernel(int* __restrict__ p, int n) {
    int i = blockIdx.x * blockDim.x + threadIdx.x;
    if (i < n) p[i] = 0;
}

// 16-wave range-partitioned scan
__global__ __launch_bounds__(1024) void scan_kernel(const int* __restrict__ deg_cnt,
                                                    int* __restrict__ row_ptr,
                                                    int* __restrict__ cursor,
                                                    float* __restrict__ dinv, int n) {
    __shared__ int ws[16];
    int t = threadIdx.x;
    int wid = t >> 6, lane = t & 63;
    const int RANGE = (n + 15) >> 4;
    const int ROUNDS = (RANGE + 63) >> 6;
    int base = wid * RANGE;

    int s = 0;
    for (int r = 0; r < ROUNDS; ++r) {
        int off = r * 64 + lane;
        int idx = base + off;
        if (off < RANGE && idx < n) s += deg_cnt[idx];
    }
    #pragma unroll
    for (int o = 32; o > 0; o >>= 1) s += __shfl_xor(s, o);
    if (lane == 0) ws[wid] = s;
    __syncthreads();

    int carry = 0;
    for (int j = 0; j < wid; ++j) carry += ws[j];

    for (int r = 0; r < ROUNDS; ++r) {
        int off = r * 64 + lane;
        int idx = base + off;
        int v = (off < RANGE && idx < n) ? deg_cnt[idx] : 0;
        int x = v;
        #pragma unroll
        for (int o = 1; o < 64; o <<= 1) {
            int y = __shfl_up(x, o);
            if (lane >= o) x += y;
        }
        if (off < RANGE && idx < n) {
            int rp = carry + x - v;
            row_ptr[idx] = rp;
            cursor[idx]  = rp;
            dinv[idx]    = rsqrtf((float)(v + 1));
        }
        carry += __shfl(x, 63);
    }
    if (t == 1023) row_ptr[n] = carry;
}

static __device__ __forceinline__ void wconv_body(const float* __restrict__ W, int i,
                                                  int Kd, int Nd,
                                                  unsigned short* __restrict__ WT) {
    int k = i / Nd, n = i % Nd;
    WT[(size_t)n * Kd + k] = f2h(W[i]);
}

// Fused setup: edge-count + 3x weight transpose (f16) + graph bounds.
__global__ void prep_kernel(const int* __restrict__ dst, int* __restrict__ deg_cnt, int E,
                            const float* __restrict__ W1, const float* __restrict__ W2,
                            const float* __restrict__ W3,
                            unsigned short* __restrict__ W1T,
                            unsigned short* __restrict__ W2T,
                            unsigned short* __restrict__ W3T,
                            const int* __restrict__ batch, int n, int ngraphs,
                            int* __restrict__ gstart) {
    int t = blockIdx.x * blockDim.x + threadIdx.x;
    if (t < E) {
        atomicAdd(&deg_cnt[dst[t]], 1);
        return;
    }
    t -= E;
    if (t < 128 * 512) { wconv_body(W1, t, 128, 512, W1T); return; }
    t -= 128 * 512;
    if (t < 512 * 256) { wconv_body(W2, t, 512, 256, W2T); return; }
    t -= 512 * 256;
    if (t < 256 * 128) { wconv_body(W3, t, 256, 128, W3T); return; }
    t -= 256 * 128;
    {
        int i = t;
        if (i >= n) return;
        int b = batch[i];
        if (i == 0) {
            for (int g = 0; g <= b; ++g) gstart[g] = 0;
        } else {
            int bp = batch[i - 1];
            if (bp != b) for (int g = bp + 1; g <= b; ++g) gstart[g] = i;
        }
        if (i == n - 1) {
            for (int g = b + 1; g <= ngraphs; ++g) gstart[g] = n;
        }
    }
}

// Fused: CSR fill (scatter) + xs = f16(x*dinv)
__global__ void fillx_kernel(const int* __restrict__ src, const int* __restrict__ dst,
                             int* __restrict__ cursor, int* __restrict__ col_idx, int E,
                             const float* __restrict__ x, const float* __restrict__ dinv,
                             unsigned short* __restrict__ xs, int nrows) {
    int t = blockIdx.x * blockDim.x + threadIdx.x;
    if (t < E) {
        int d = dst[t];
        int pos = atomicAdd(&cursor[d], 1);
        col_idx[pos] = src[t];
    } else {
        int u = t - E;
        int row = u >> 5, q = u & 31;
        if (row >= nrows) return;
        float di = dinv[row];
        f32x4 v = *reinterpret_cast<const f32x4*>(&x[(size_t)row * 128 + q * 4]);
        ushort4 o;
        o.x = f2h(v.x * di); o.y = f2h(v.y * di);
        o.z = f2h(v.z * di); o.w = f2h(v.w * di);
        *reinterpret_cast<ushort4*>(&xs[(size_t)row * 128 + q * 4]) = o;
    }
}

// ---------------------------------------------------------------------------
// Aggregation: out[i] = dinv[i]*(hs[i] + sum_{e in(i)} hs[src]) (+bias)(relu)
// ONE WAVE PER NODE (4 nodes/block). EL lanes per edge (16 for F=128, 32 for
// F=256), each lane loads uint4 = 8 f16 (16B). EPS=64/EL edges per step,
// unroll 4 -> 4*EPS edges in flight. Fold via shfl_xor(EL..32).
// ---------------------------------------------------------------------------
template <int F, bool BIAS, bool RELU>
__global__ __launch_bounds__(256) void agg_kernel(const unsigned short* __restrict__ hs,
                                                  const float* __restrict__ dinv,
                                                  const int* __restrict__ row_ptr,
                                                  const int* __restrict__ col_idx,
                                                  const float* __restrict__ bias,
                                                  unsigned short* __restrict__ out, int n) {
    constexpr int EL  = F / 8;          // lanes per edge: 16 (F=128) / 32 (F=256)
    constexpr int EPS = 64 / EL;        // edges per step: 4 / 2
    int tid = threadIdx.x;
    int wid = tid >> 6, lane = tid & 63;
    int eg = lane / EL, le = lane % EL; // edge-group, lane-in-group
    int i = blockIdx.x * 4 + wid;
    if (i >= n) return;                 // wave-uniform; no barriers in kernel
    int e0 = row_ptr[i], e1 = row_ptr[i + 1];

    float acc[8];
    #pragma unroll
    for (int v = 0; v < 8; ++v) acc[v] = 0.f;

    // group 0 seeds with the self row
    if (eg == 0) {
        uint4 u = *reinterpret_cast<const uint4*>(&hs[(size_t)i * F + le * 8]);
        acc[0] = hu_lo(u.x); acc[1] = hu_hi(u.x);
        acc[2] = hu_lo(u.y); acc[3] = hu_hi(u.y);
        acc[4] = hu_lo(u.z); acc[5] = hu_hi(u.z);
        acc[6] = hu_lo(u.w); acc[7] = hu_hi(u.w);
    }

    for (int base = e0; base < e1; base += 64) {
        int rem = e1 - base;
        int mm = rem < 64 ? rem : 64;
        int myidx = col_idx[base + (lane < mm ? lane : 0)];
        for (int j0 = 0; j0 < mm; j0 += 4 * EPS) {
            #pragma unroll
            for (int k = 0; k < 4; ++k) {
                int j = j0 + k * EPS + eg;
                int jc = j < mm ? j : 0;
                int srcn = __shfl(myidx, jc);
                float w = (j < mm) ? 1.f : 0.f;
                uint4 u = *reinterpret_cast<const uint4*>(&hs[(size_t)srcn * F + le * 8]);
                acc[0] = fmaf(hu_lo(u.x), w, acc[0]);
                acc[1] = fmaf(hu_hi(u.x), w, acc[1]);
                acc[2] = fmaf(hu_lo(u.y), w, acc[2]);
                acc[3] = fmaf(hu_hi(u.y), w, acc[3]);
                acc[4] = fmaf(hu_lo(u.z), w, acc[4]);
                acc[5] = fmaf(hu_hi(u.z), w, acc[5]);
                acc[6] = fmaf(hu_lo(u.w), w, acc[6]);
                acc[7] = fmaf(hu_hi(u.w), w, acc[7]);
            }
        }
    }

    // fold edge groups: EL=16 -> xor 16,32 ; EL=32 -> xor 32
    #pragma unroll
    for (int o = EL; o < 64; o <<= 1)
        #pragma unroll
        for (int v = 0; v < 8; ++v) acc[v] += __shfl_xor(acc[v], o);

    if (eg == 0) {
        float di = dinv[i];
        unsigned short ov[8];
        #pragma unroll
        for (int v = 0; v < 8; ++v) {
            float r = di * acc[v];
            if (BIAS) r += bias[le * 8 + v];
            if (RELU) r = fmaxf(r, 0.f);
            ov[v] = f2h(r);
        }
        uint4 o;
        o.x = (unsigned)ov[0] | ((unsigned)ov[1] << 16);
        o.y = (unsigned)ov[2] | ((unsigned)ov[3] << 16);
        o.z = (unsigned)ov[4] | ((unsigned)ov[5] << 16);
        o.w = (unsigned)ov[6] | ((unsigned)ov[7] << 16);
        *reinterpret_cast<uint4*>(&out[(size_t)i * F + le * 8]) = o;
    }
}

// ---------------------------------------------------------------------------
// MFMA f16 GEMM: C[M,N] = A[M,K] @ W[K,N] (+bias)(relu)(*dinv[row]) -> f16
// A [M][K] f16, WT [N][K] f16. BK=64, 256 threads = 4 waves (2x2).
// LDS XOR-swizzled (ushort units): idx = row*64 + (k ^ ((row&7)<<3))
// ---------------------------------------------------------------------------
template <int K, int N, int BM, int BN, bool BIAS, bool RELU, bool SCALE>
__global__ __launch_bounds__(256) void gemm_mfma(const unsigned short* __restrict__ A,
                                                 const unsigned short* __restrict__ WT,
                                                 const float* __restrict__ bias,
                                                 const float* __restrict__ dinvp,
                                                 unsigned short* __restrict__ C, int M) {
    constexpr int BK = 64;
    constexpr int MI = BM / 32;
    constexpr int WN = BN / 32;
    __shared__ unsigned short As[BM * BK];
    __shared__ unsigned short Bs[BN * BK];

    const int tid = threadIdx.x;
    const int wid = tid >> 6;
    const int lane16 = tid & 15;
    const int quad = (tid >> 4) & 3;
    const int wm = (wid >> 1) * (BM / 2);
    const int wn = (wid & 1) * (BN / 2);
    const int bm = blockIdx.x * BM;
    const int bn = blockIdx.y * BN;

    f32x4 acc[MI][WN];
    #pragma unroll
    for (int mi = 0; mi < MI; ++mi)
        #pragma unroll
        for (int ni = 0; ni < WN; ++ni) acc[mi][ni] = (f32x4)(0.f);

    for (int kt = 0; kt < K / BK; ++kt) {
        #pragma unroll
        for (int c = 0; c < (BM * 8) / 256; ++c) {
            int ch = tid + c * 256;
            int row = ch >> 3, kc = ch & 7;
            int gm = bm + row;
            u16x8 av = (u16x8)(0);
            if (gm < M) av = *reinterpret_cast<const u16x8*>(&A[(size_t)gm * K + kt * BK + kc * 8]);
            *reinterpret_cast<u16x8*>(&As[row * 64 + ((kc * 8) ^ ((row & 7) << 3))]) = av;
        }
        #pragma unroll
        for (int c = 0; c < (BN * 8) / 256; ++c) {
            int ch = tid + c * 256;
            int row = ch >> 3, kc = ch & 7;
            u16x8 bv = *reinterpret_cast<const u16x8*>(&WT[(size_t)(bn + row) * K + kt * BK + kc * 8]);
            *reinterpret_cast<u16x8*>(&Bs[row * 64 + ((kc * 8) ^ ((row & 7) << 3))]) = bv;
        }
        __syncthreads();

        #pragma unroll
        for (int ks = 0; ks < 2; ++ks) {
            f16x8 af[MI], bf[WN];
            #pragma unroll
            for (int mi = 0; mi < MI; ++mi) {
                int row = wm + mi * 16 + lane16;
                int kidx = ks * 32 + quad * 8;
                af[mi] = *reinterpret_cast<f16x8*>(&As[row * 64 + (kidx ^ ((row & 7) << 3))]);
            }
            #pragma unroll
            for (int ni = 0; ni < WN; ++ni) {
                int row = wn + ni * 16 + lane16;
                int kidx = ks * 32 + quad * 8;
                bf[ni] = *reinterpret_cast<f16x8*>(&Bs[row * 64 + (kidx ^ ((row & 7) << 3))]);
            }
            #pragma unroll
            for (int mi = 0; mi < MI; ++mi)
                #pragma unroll
                for (int ni = 0; ni < WN; ++ni)
                    acc[mi][ni] = __builtin_amdgcn_mfma_f32_16x16x32_f16(af[mi], bf[ni], acc[mi][ni], 0, 0, 0);
        }
        __syncthreads();
    }

    #pragma unroll
    for (int mi = 0; mi < MI; ++mi) {
        #pragma unroll
        for (int r = 0; r < 4; ++r) {
            int gm = bm + wm + mi * 16 + quad * 4 + r;
            if (gm >= M) continue;
            float sc = SCALE ? dinvp[gm] : 1.f;
            #pragma unroll
            for (int ni = 0; ni < WN; ++ni) {
                int gn = bn + wn + ni * 16 + lane16;
                float v = acc[mi][ni][r];
                if (BIAS) v += bias[gn];
                if (RELU) v = fmaxf(v, 0.f);
                if (SCALE) v *= sc;
                C[(size_t)gm * N + gn] = f2h(v);
            }
        }
    }
}

// pool stage 1: grid (G, 8), 256 threads = 2 rows x 128 cols, rows strided by 16
__global__ void pool_partial_kernel(const unsigned short* __restrict__ A,
                                    const int* __restrict__ gstart,
                                    float* __restrict__ partial) {
    __shared__ float sd[256];
    int g = blockIdx.x, y = blockIdx.y;
    int t = threadIdx.x;
    int c = t & 127, r = t >> 7;
    int s0 = gstart[g], s1 = gstart[g + 1];
    float s = 0.f;
    for (int i = s0 + y * 2 + r; i < s1; i += 16)
        s += h2f(A[(size_t)i * 128 + c]);
    sd[t] = s;
    __syncthreads();
    if (t < 128) partial[(size_t)(g * 8 + y) * 128 + c] = sd[t] + sd[t + 128];
}

// pool stage 2 + final linear: 64 blocks x 128 threads.
__global__ void poolfinal_kernel(const float* __restrict__ partial,
                                 const int* __restrict__ gstart,
                                 const float* __restrict__ Wl, const float* __restrict__ bl,
                                 float* __restrict__ out) {
    __shared__ float2 red[128];
    int g = blockIdx.x, c = threadIdx.x;
    float s = 0.f;
    #pragma unroll
    for (int y = 0; y < 8; ++y) s += partial[(size_t)(g * 8 + y) * 128 + c];
    int cnt = gstart[g + 1] - gstart[g];
    if (cnt < 1) cnt = 1;
    float p = s / (float)cnt;
    red[c] = make_float2(p * Wl[c * 2 + 0], p * Wl[c * 2 + 1]);
    __syncthreads();
    for (int off = 64; off > 0; off >>= 1) {
        if (c < off) {
            red[c].x += red[c + off].x;
            red[c].y += red[c + off].y;
        }
        __syncthreads();
    }
    if (c == 0) {
        out[g * 2 + 0] = red[0].x + bl[0];
        out[g * 2 + 1] = red[0].y + bl[1];
    }
}

extern "C" void kernel_launch(void* const* d_in, const int* in_sizes, int n_in,
                              void* d_out, int out_size, void* d_ws, size_t ws_size,
                              hipStream_t stream) {
    const float* x   = (const float*)d_in[0];
    const int*   ei  = (const int*)d_in[1];
    const int*   bat = (const int*)d_in[2];
    const float* W1  = (const float*)d_in[3];
    const float* b1  = (const float*)d_in[4];
    const float* W2  = (const float*)d_in[5];
    const float* b2  = (const float*)d_in[6];
    const float* W3  = (const float*)d_in[7];
    const float* b3  = (const float*)d_in[8];
    const float* Wl  = (const float*)d_in[9];
    const float* bl  = (const float*)d_in[10];
    float* out = (float*)d_out;

    const int N = N_NODES_C;
    const int E = in_sizes[1] / 2;
    const int G = N_GRAPHS_C;

    const int* src = ei;
    const int* dst = ei + E;

    // -------- workspace layout --------
    unsigned short* xs  = (unsigned short*)d_ws;         // N*128 f16 (x*dinv)
    unsigned short* A1b = xs  + (size_t)N * 128;         // N*128
    unsigned short* H1  = A1b + (size_t)N * 128;         // N*512
    unsigned short* T2s = H1  + (size_t)N * 512;         // N*256 ((H1@W2)*dinv)
    unsigned short* H2  = T2s + (size_t)N * 256;         // N*256
    unsigned short* T3s = H2  + (size_t)N * 256;         // N*128 ((H2@W3)*dinv)
    unsigned short* A3  = T3s + (size_t)N * 128;         // N*128
    unsigned short* W1T = A3  + (size_t)N * 128;         // 512*128 f16 [N][K]
    unsigned short* W2T = W1T + 512 * 128;               // 256*512
    unsigned short* W3T = W2T + 256 * 512;               // 128*256
    int*   deg_cnt = (int*)(W3T + 128 * 256);            // N
    int*   row_ptr = deg_cnt + N;                        // N+1
    int*   cursor  = row_ptr + (N + 1);                  // N
    int*   col_idx = cursor + N;                         // E
    float* dinv    = (float*)(col_idx + E);              // N
    int*   gstart  = (int*)(dinv + N);                   // G+1 (+pad)
    float* partial = (float*)(gstart + (G + 4));         // G*8*128 f32

    // --- setup ---
    zero_kernel<<<(N + 255) / 256, 256, 0, stream>>>(deg_cnt, N);
    {
        int total = E + 128 * 512 + 512 * 256 + 256 * 128 + N;
        prep_kernel<<<(total + 255) / 256, 256, 0, stream>>>(dst, deg_cnt, E,
                                                             W1, W2, W3, W1T, W2T, W3T,
                                                             bat, N, G, gstart);
    }
    scan_kernel<<<1, 1024, 0, stream>>>(deg_cnt, row_ptr, cursor, dinv, N);
    {
        int total = E + N * 32;
        fillx_kernel<<<(total + 255) / 256, 256, 0, stream>>>(src, dst, cursor, col_idx, E,
                                                              x, dinv, xs, N);
    }

    const int MB128 = (N + 127) / 128;   // 157
    const int MB64  = (N + 63) / 64;     // 313
    const int AGGB  = (N + 3) / 4;       // 5000 (one wave per node)

    // --- layer 1: A1 = Ahat x, H1 = relu(A1 @ W1 + b1) ---
    agg_kernel<128, false, false><<<AGGB, 256, 0, stream>>>(xs, dinv, row_ptr, col_idx, nullptr, A1b, N);
    {
        dim3 grid(MB128, 512 / 128);
        gemm_mfma<128, 512, 128, 128, true, true, false><<<grid, 256, 0, stream>>>(A1b, W1T, b1, nullptr, H1, N);
    }
    // --- layer 2: T2s = (H1 @ W2)*dinv, H2 = relu(dinv*(T2s_i + sum) + b2) ---
    {
        dim3 grid(MB64, 256 / 128);
        gemm_mfma<512, 256, 64, 128, false, false, true><<<grid, 256, 0, stream>>>(H1, W2T, nullptr, dinv, T2s, N);
    }
    agg_kernel<256, true, true><<<AGGB, 256, 0, stream>>>(T2s, dinv, row_ptr, col_idx, b2, H2, N);
    // --- layer 3: T3s = (H2 @ W3)*dinv, A3 = dinv*(T3s_i + sum) + b3 ---
    {
        dim3 grid(MB64, 128 / 64);
        gemm_mfma<256, 128, 64, 64, false, false, true><<<grid, 256, 0, stream>>>(H2, W3T, nullptr, dinv, T3s, N);
    }
    agg_kernel<128, true, false><<<AGGB, 256, 0, stream>>>(T3s, dinv, row_ptr, col_idx, b3, A3, N);

    // --- pool (two-stage) + final linear ---
    {
        dim3 grid(G, 8);
        pool_partial_kernel<<<grid, 256, 0, stream>>>(A3, gstart, partial);
    }
    poolfinal_kernel<<<G, 128, 0, stream>>>(partial, gstart, Wl, bl, out);
}

// Round 15
// 154.173 us; speedup vs baseline: 1.0667x; 1.0061x over previous
//
#include <hip/hip_runtime.h>
#include <hip/hip_bf16.h>

// ---------------------------------------------------------------------------
// GCN: 3x gcn_conv + global_mean_pool + linear
//   h' = D^-1/2 (A+I) D^-1/2 (h W) + b
// Layer1 aggregates BEFORE GEMM ((AX)W == A(XW)), layers 2/3 after.
// dinv FOLDED into stored features; aggregation = pure gather+sum.
// F16 features + weights. Agg: ONE WAVE PER NODE; EL-lane edge groups,
// 16B/lane uint4 gathers, unroll 4.
// GEMMs: LDS-staged f16 MFMA, XOR-swizzled, single weight plane.
// Pool+final: ONE kernel (64 blocks; merged R15 — saves a dispatch+gap).
// Scan: 16-wave range-partitioned. 11 dispatches.
// ---------------------------------------------------------------------------

#define N_NODES_C  20000
#define N_GRAPHS_C 64
#define HID_C      512

typedef __attribute__((ext_vector_type(8))) _Float16 f16x8;
typedef __attribute__((ext_vector_type(8))) unsigned short u16x8;
typedef __attribute__((ext_vector_type(4))) float f32x4;

static __device__ __forceinline__ unsigned short f2h(float f) {
    _Float16 h = (_Float16)f;
    return __builtin_bit_cast(unsigned short, h);
}
static __device__ __forceinline__ float h2f(unsigned short u) {
    return (float)__builtin_bit_cast(_Float16, u);
}
static __device__ __forceinline__ float hu_lo(unsigned u) {
    return (float)__builtin_bit_cast(_Float16, (unsigned short)(u & 0xffffu));
}
static __device__ __forceinline__ float hu_hi(unsigned u) {
    return (float)__builtin_bit_cast(_Float16, (unsigned short)(u >> 16));
}

// custom zero for deg_cnt
__global__ void zero_kernel(int* __restrict__ p, int n) {
    int i = blockIdx.x * blockDim.x + threadIdx.x;
    if (i < n) p[i] = 0;
}

// 16-wave range-partitioned scan
__global__ __launch_bounds__(1024) void scan_kernel(const int* __restrict__ deg_cnt,
                                                    int* __restrict__ row_ptr,
                                                    int* __restrict__ cursor,
                                                    float* __restrict__ dinv, int n) {
    __shared__ int ws[16];
    int t = threadIdx.x;
    int wid = t >> 6, lane = t & 63;
    const int RANGE = (n + 15) >> 4;
    const int ROUNDS = (RANGE + 63) >> 6;
    int base = wid * RANGE;

    int s = 0;
    for (int r = 0; r < ROUNDS; ++r) {
        int off = r * 64 + lane;
        int idx = base + off;
        if (off < RANGE && idx < n) s += deg_cnt[idx];
    }
    #pragma unroll
    for (int o = 32; o > 0; o >>= 1) s += __shfl_xor(s, o);
    if (lane == 0) ws[wid] = s;
    __syncthreads();

    int carry = 0;
    for (int j = 0; j < wid; ++j) carry += ws[j];

    for (int r = 0; r < ROUNDS; ++r) {
        int off = r * 64 + lane;
        int idx = base + off;
        int v = (off < RANGE && idx < n) ? deg_cnt[idx] : 0;
        int x = v;
        #pragma unroll
        for (int o = 1; o < 64; o <<= 1) {
            int y = __shfl_up(x, o);
            if (lane >= o) x += y;
        }
        if (off < RANGE && idx < n) {
            int rp = carry + x - v;
            row_ptr[idx] = rp;
            cursor[idx]  = rp;
            dinv[idx]    = rsqrtf((float)(v + 1));
        }
        carry += __shfl(x, 63);
    }
    if (t == 1023) row_ptr[n] = carry;
}

static __device__ __forceinline__ void wconv_body(const float* __restrict__ W, int i,
                                                  int Kd, int Nd,
                                                  unsigned short* __restrict__ WT) {
    int k = i / Nd, n = i % Nd;
    WT[(size_t)n * Kd + k] = f2h(W[i]);
}

// Fused setup: edge-count + 3x weight transpose (f16) + graph bounds.
__global__ void prep_kernel(const int* __restrict__ dst, int* __restrict__ deg_cnt, int E,
                            const float* __restrict__ W1, const float* __restrict__ W2,
                            const float* __restrict__ W3,
                            unsigned short* __restrict__ W1T,
                            unsigned short* __restrict__ W2T,
                            unsigned short* __restrict__ W3T,
                            const int* __restrict__ batch, int n, int ngraphs,
                            int* __restrict__ gstart) {
    int t = blockIdx.x * blockDim.x + threadIdx.x;
    if (t < E) {
        atomicAdd(&deg_cnt[dst[t]], 1);
        return;
    }
    t -= E;
    if (t < 128 * 512) { wconv_body(W1, t, 128, 512, W1T); return; }
    t -= 128 * 512;
    if (t < 512 * 256) { wconv_body(W2, t, 512, 256, W2T); return; }
    t -= 512 * 256;
    if (t < 256 * 128) { wconv_body(W3, t, 256, 128, W3T); return; }
    t -= 256 * 128;
    {
        int i = t;
        if (i >= n) return;
        int b = batch[i];
        if (i == 0) {
            for (int g = 0; g <= b; ++g) gstart[g] = 0;
        } else {
            int bp = batch[i - 1];
            if (bp != b) for (int g = bp + 1; g <= b; ++g) gstart[g] = i;
        }
        if (i == n - 1) {
            for (int g = b + 1; g <= ngraphs; ++g) gstart[g] = n;
        }
    }
}

// Fused: CSR fill (scatter) + xs = f16(x*dinv)
__global__ void fillx_kernel(const int* __restrict__ src, const int* __restrict__ dst,
                             int* __restrict__ cursor, int* __restrict__ col_idx, int E,
                             const float* __restrict__ x, const float* __restrict__ dinv,
                             unsigned short* __restrict__ xs, int nrows) {
    int t = blockIdx.x * blockDim.x + threadIdx.x;
    if (t < E) {
        int d = dst[t];
        int pos = atomicAdd(&cursor[d], 1);
        col_idx[pos] = src[t];
    } else {
        int u = t - E;
        int row = u >> 5, q = u & 31;
        if (row >= nrows) return;
        float di = dinv[row];
        f32x4 v = *reinterpret_cast<const f32x4*>(&x[(size_t)row * 128 + q * 4]);
        ushort4 o;
        o.x = f2h(v.x * di); o.y = f2h(v.y * di);
        o.z = f2h(v.z * di); o.w = f2h(v.w * di);
        *reinterpret_cast<ushort4*>(&xs[(size_t)row * 128 + q * 4]) = o;
    }
}

// ---------------------------------------------------------------------------
// Aggregation: out[i] = dinv[i]*(hs[i] + sum_{e in(i)} hs[src]) (+bias)(relu)
// ONE WAVE PER NODE (4 nodes/block). EL lanes per edge (16 for F=128, 32 for
// F=256), each lane loads uint4 = 8 f16 (16B). EPS=64/EL edges per step,
// unroll 4 -> 4*EPS edges in flight. Fold via shfl_xor(EL..32).
// ---------------------------------------------------------------------------
template <int F, bool BIAS, bool RELU>
__global__ __launch_bounds__(256) void agg_kernel(const unsigned short* __restrict__ hs,
                                                  const float* __restrict__ dinv,
                                                  const int* __restrict__ row_ptr,
                                                  const int* __restrict__ col_idx,
                                                  const float* __restrict__ bias,
                                                  unsigned short* __restrict__ out, int n) {
    constexpr int EL  = F / 8;          // lanes per edge: 16 (F=128) / 32 (F=256)
    constexpr int EPS = 64 / EL;        // edges per step: 4 / 2
    int tid = threadIdx.x;
    int wid = tid >> 6, lane = tid & 63;
    int eg = lane / EL, le = lane % EL; // edge-group, lane-in-group
    int i = blockIdx.x * 4 + wid;
    if (i >= n) return;                 // wave-uniform; no barriers in kernel
    int e0 = row_ptr[i], e1 = row_ptr[i + 1];

    float acc[8];
    #pragma unroll
    for (int v = 0; v < 8; ++v) acc[v] = 0.f;

    // group 0 seeds with the self row
    if (eg == 0) {
        uint4 u = *reinterpret_cast<const uint4*>(&hs[(size_t)i * F + le * 8]);
        acc[0] = hu_lo(u.x); acc[1] = hu_hi(u.x);
        acc[2] = hu_lo(u.y); acc[3] = hu_hi(u.y);
        acc[4] = hu_lo(u.z); acc[5] = hu_hi(u.z);
        acc[6] = hu_lo(u.w); acc[7] = hu_hi(u.w);
    }

    for (int base = e0; base < e1; base += 64) {
        int rem = e1 - base;
        int mm = rem < 64 ? rem : 64;
        int myidx = col_idx[base + (lane < mm ? lane : 0)];
        for (int j0 = 0; j0 < mm; j0 += 4 * EPS) {
            #pragma unroll
            for (int k = 0; k < 4; ++k) {
                int j = j0 + k * EPS + eg;
                int jc = j < mm ? j : 0;
                int srcn = __shfl(myidx, jc);
                float w = (j < mm) ? 1.f : 0.f;
                uint4 u = *reinterpret_cast<const uint4*>(&hs[(size_t)srcn * F + le * 8]);
                acc[0] = fmaf(hu_lo(u.x), w, acc[0]);
                acc[1] = fmaf(hu_hi(u.x), w, acc[1]);
                acc[2] = fmaf(hu_lo(u.y), w, acc[2]);
                acc[3] = fmaf(hu_hi(u.y), w, acc[3]);
                acc[4] = fmaf(hu_lo(u.z), w, acc[4]);
                acc[5] = fmaf(hu_hi(u.z), w, acc[5]);
                acc[6] = fmaf(hu_lo(u.w), w, acc[6]);
                acc[7] = fmaf(hu_hi(u.w), w, acc[7]);
            }
        }
    }

    // fold edge groups: EL=16 -> xor 16,32 ; EL=32 -> xor 32
    #pragma unroll
    for (int o = EL; o < 64; o <<= 1)
        #pragma unroll
        for (int v = 0; v < 8; ++v) acc[v] += __shfl_xor(acc[v], o);

    if (eg == 0) {
        float di = dinv[i];
        unsigned short ov[8];
        #pragma unroll
        for (int v = 0; v < 8; ++v) {
            float r = di * acc[v];
            if (BIAS) r += bias[le * 8 + v];
            if (RELU) r = fmaxf(r, 0.f);
            ov[v] = f2h(r);
        }
        uint4 o;
        o.x = (unsigned)ov[0] | ((unsigned)ov[1] << 16);
        o.y = (unsigned)ov[2] | ((unsigned)ov[3] << 16);
        o.z = (unsigned)ov[4] | ((unsigned)ov[5] << 16);
        o.w = (unsigned)ov[6] | ((unsigned)ov[7] << 16);
        *reinterpret_cast<uint4*>(&out[(size_t)i * F + le * 8]) = o;
    }
}

// ---------------------------------------------------------------------------
// MFMA f16 GEMM: C[M,N] = A[M,K] @ W[K,N] (+bias)(relu)(*dinv[row]) -> f16
// A [M][K] f16, WT [N][K] f16. BK=64, 256 threads = 4 waves (2x2).
// LDS XOR-swizzled (ushort units): idx = row*64 + (k ^ ((row&7)<<3))
// ---------------------------------------------------------------------------
template <int K, int N, int BM, int BN, bool BIAS, bool RELU, bool SCALE>
__global__ __launch_bounds__(256) void gemm_mfma(const unsigned short* __restrict__ A,
                                                 const unsigned short* __restrict__ WT,
                                                 const float* __restrict__ bias,
                                                 const float* __restrict__ dinvp,
                                                 unsigned short* __restrict__ C, int M) {
    constexpr int BK = 64;
    constexpr int MI = BM / 32;
    constexpr int WN = BN / 32;
    __shared__ unsigned short As[BM * BK];
    __shared__ unsigned short Bs[BN * BK];

    const int tid = threadIdx.x;
    const int wid = tid >> 6;
    const int lane16 = tid & 15;
    const int quad = (tid >> 4) & 3;
    const int wm = (wid >> 1) * (BM / 2);
    const int wn = (wid & 1) * (BN / 2);
    const int bm = blockIdx.x * BM;
    const int bn = blockIdx.y * BN;

    f32x4 acc[MI][WN];
    #pragma unroll
    for (int mi = 0; mi < MI; ++mi)
        #pragma unroll
        for (int ni = 0; ni < WN; ++ni) acc[mi][ni] = (f32x4)(0.f);

    for (int kt = 0; kt < K / BK; ++kt) {
        #pragma unroll
        for (int c = 0; c < (BM * 8) / 256; ++c) {
            int ch = tid + c * 256;
            int row = ch >> 3, kc = ch & 7;
            int gm = bm + row;
            u16x8 av = (u16x8)(0);
            if (gm < M) av = *reinterpret_cast<const u16x8*>(&A[(size_t)gm * K + kt * BK + kc * 8]);
            *reinterpret_cast<u16x8*>(&As[row * 64 + ((kc * 8) ^ ((row & 7) << 3))]) = av;
        }
        #pragma unroll
        for (int c = 0; c < (BN * 8) / 256; ++c) {
            int ch = tid + c * 256;
            int row = ch >> 3, kc = ch & 7;
            u16x8 bv = *reinterpret_cast<const u16x8*>(&WT[(size_t)(bn + row) * K + kt * BK + kc * 8]);
            *reinterpret_cast<u16x8*>(&Bs[row * 64 + ((kc * 8) ^ ((row & 7) << 3))]) = bv;
        }
        __syncthreads();

        #pragma unroll
        for (int ks = 0; ks < 2; ++ks) {
            f16x8 af[MI], bf[WN];
            #pragma unroll
            for (int mi = 0; mi < MI; ++mi) {
                int row = wm + mi * 16 + lane16;
                int kidx = ks * 32 + quad * 8;
                af[mi] = *reinterpret_cast<f16x8*>(&As[row * 64 + (kidx ^ ((row & 7) << 3))]);
            }
            #pragma unroll
            for (int ni = 0; ni < WN; ++ni) {
                int row = wn + ni * 16 + lane16;
                int kidx = ks * 32 + quad * 8;
                bf[ni] = *reinterpret_cast<f16x8*>(&Bs[row * 64 + (kidx ^ ((row & 7) << 3))]);
            }
            #pragma unroll
            for (int mi = 0; mi < MI; ++mi)
                #pragma unroll
                for (int ni = 0; ni < WN; ++ni)
                    acc[mi][ni] = __builtin_amdgcn_mfma_f32_16x16x32_f16(af[mi], bf[ni], acc[mi][ni], 0, 0, 0);
        }
        __syncthreads();
    }

    #pragma unroll
    for (int mi = 0; mi < MI; ++mi) {
        #pragma unroll
        for (int r = 0; r < 4; ++r) {
            int gm = bm + wm + mi * 16 + quad * 4 + r;
            if (gm >= M) continue;
            float sc = SCALE ? dinvp[gm] : 1.f;
            #pragma unroll
            for (int ni = 0; ni < WN; ++ni) {
                int gn = bn + wn + ni * 16 + lane16;
                float v = acc[mi][ni][r];
                if (BIAS) v += bias[gn];
                if (RELU) v = fmaxf(v, 0.f);
                if (SCALE) v *= sc;
                C[(size_t)gm * N + gn] = f2h(v);
            }
        }
    }
}

// ---------------------------------------------------------------------------
// Merged pool + final linear: ONE block per graph. 16 row-slots x 16-lane
// 16B chunks; LDS fold over slots; mean; dot with Wl; write out[g*2..].
// Deterministic (fixed slot order, fixed tree).
// ---------------------------------------------------------------------------
__global__ __launch_bounds__(256) void poolall_kernel(const unsigned short* __restrict__ A,
                                                      const int* __restrict__ gstart,
                                                      const float* __restrict__ Wl,
                                                      const float* __restrict__ bl,
                                                      float* __restrict__ out) {
    __shared__ float sd[16][128];
    __shared__ float2 red[128];
    int g = blockIdx.x;
    int t = threadIdx.x;
    int slot = t >> 4, ch = t & 15;
    int s0 = gstart[g], s1 = gstart[g + 1];

    float acc[8] = {0.f, 0.f, 0.f, 0.f, 0.f, 0.f, 0.f, 0.f};
    for (int i = s0 + slot; i < s1; i += 16) {
        uint4 u = *reinterpret_cast<const uint4*>(&A[(size_t)i * 128 + ch * 8]);
        acc[0] += hu_lo(u.x); acc[1] += hu_hi(u.x);
        acc[2] += hu_lo(u.y); acc[3] += hu_hi(u.y);
        acc[4] += hu_lo(u.z); acc[5] += hu_hi(u.z);
        acc[6] += hu_lo(u.w); acc[7] += hu_hi(u.w);
    }
    #pragma unroll
    for (int v = 0; v < 8; ++v) sd[slot][ch * 8 + v] = acc[v];
    __syncthreads();

    int cnt = s1 - s0;
    if (cnt < 1) cnt = 1;
    if (t < 128) {
        float p = 0.f;
        #pragma unroll
        for (int s = 0; s < 16; ++s) p += sd[s][t];
        p /= (float)cnt;
        red[t] = make_float2(p * Wl[t * 2 + 0], p * Wl[t * 2 + 1]);
    }
    __syncthreads();
    for (int off = 64; off > 0; off >>= 1) {
        if (t < off) {
            red[t].x += red[t + off].x;
            red[t].y += red[t + off].y;
        }
        __syncthreads();
    }
    if (t == 0) {
        out[g * 2 + 0] = red[0].x + bl[0];
        out[g * 2 + 1] = red[0].y + bl[1];
    }
}

extern "C" void kernel_launch(void* const* d_in, const int* in_sizes, int n_in,
                              void* d_out, int out_size, void* d_ws, size_t ws_size,
                              hipStream_t stream) {
    const float* x   = (const float*)d_in[0];
    const int*   ei  = (const int*)d_in[1];
    const int*   bat = (const int*)d_in[2];
    const float* W1  = (const float*)d_in[3];
    const float* b1  = (const float*)d_in[4];
    const float* W2  = (const float*)d_in[5];
    const float* b2  = (const float*)d_in[6];
    const float* W3  = (const float*)d_in[7];
    const float* b3  = (const float*)d_in[8];
    const float* Wl  = (const float*)d_in[9];
    const float* bl  = (const float*)d_in[10];
    float* out = (float*)d_out;

    const int N = N_NODES_C;
    const int E = in_sizes[1] / 2;
    const int G = N_GRAPHS_C;

    const int* src = ei;
    const int* dst = ei + E;

    // -------- workspace layout --------
    unsigned short* xs  = (unsigned short*)d_ws;         // N*128 f16 (x*dinv)
    unsigned short* A1b = xs  + (size_t)N * 128;         // N*128
    unsigned short* H1  = A1b + (size_t)N * 128;         // N*512
    unsigned short* T2s = H1  + (size_t)N * 512;         // N*256 ((H1@W2)*dinv)
    unsigned short* H2  = T2s + (size_t)N * 256;         // N*256
    unsigned short* T3s = H2  + (size_t)N * 256;         // N*128 ((H2@W3)*dinv)
    unsigned short* A3  = T3s + (size_t)N * 128;         // N*128
    unsigned short* W1T = A3  + (size_t)N * 128;         // 512*128 f16 [N][K]
    unsigned short* W2T = W1T + 512 * 128;               // 256*512
    unsigned short* W3T = W2T + 256 * 512;               // 128*256
    int*   deg_cnt = (int*)(W3T + 128 * 256);            // N
    int*   row_ptr = deg_cnt + N;                        // N+1
    int*   cursor  = row_ptr + (N + 1);                  // N
    int*   col_idx = cursor + N;                         // E
    float* dinv    = (float*)(col_idx + E);              // N
    int*   gstart  = (int*)(dinv + N);                   // G+1 (+pad)

    // --- setup ---
    zero_kernel<<<(N + 255) / 256, 256, 0, stream>>>(deg_cnt, N);
    {
        int total = E + 128 * 512 + 512 * 256 + 256 * 128 + N;
        prep_kernel<<<(total + 255) / 256, 256, 0, stream>>>(dst, deg_cnt, E,
                                                             W1, W2, W3, W1T, W2T, W3T,
                                                             bat, N, G, gstart);
    }
    scan_kernel<<<1, 1024, 0, stream>>>(deg_cnt, row_ptr, cursor, dinv, N);
    {
        int total = E + N * 32;
        fillx_kernel<<<(total + 255) / 256, 256, 0, stream>>>(src, dst, cursor, col_idx, E,
                                                              x, dinv, xs, N);
    }

    const int MB128 = (N + 127) / 128;   // 157
    const int MB64  = (N + 63) / 64;     // 313
    const int AGGB  = (N + 3) / 4;       // 5000 (one wave per node)

    // --- layer 1: A1 = Ahat x, H1 = relu(A1 @ W1 + b1) ---
    agg_kernel<128, false, false><<<AGGB, 256, 0, stream>>>(xs, dinv, row_ptr, col_idx, nullptr, A1b, N);
    {
        dim3 grid(MB128, 512 / 128);
        gemm_mfma<128, 512, 128, 128, true, true, false><<<grid, 256, 0, stream>>>(A1b, W1T, b1, nullptr, H1, N);
    }
    // --- layer 2: T2s = (H1 @ W2)*dinv, H2 = relu(dinv*(T2s_i + sum) + b2) ---
    {
        dim3 grid(MB64, 256 / 128);
        gemm_mfma<512, 256, 64, 128, false, false, true><<<grid, 256, 0, stream>>>(H1, W2T, nullptr, dinv, T2s, N);
    }
    agg_kernel<256, true, true><<<AGGB, 256, 0, stream>>>(T2s, dinv, row_ptr, col_idx, b2, H2, N);
    // --- layer 3: T3s = (H2 @ W3)*dinv, A3 = dinv*(T3s_i + sum) + b3 ---
    {
        dim3 grid(MB64, 128 / 64);
        gemm_mfma<256, 128, 64, 64, false, false, true><<<grid, 256, 0, stream>>>(H2, W3T, nullptr, dinv, T3s, N);
    }
    agg_kernel<128, true, false><<<AGGB, 256, 0, stream>>>(T3s, dinv, row_ptr, col_idx, b3, A3, N);

    // --- merged pool + final linear ---
    poolall_kernel<<<G, 256, 0, stream>>>(A3, gstart, Wl, bl, out);
}